// Round 7
// baseline (465.238 us; speedup 1.0000x reference)
//
#include <hip/hip_runtime.h>
#include <hip/hip_bf16.h>

#define B_      2048
#define R_      333
#define MAXI_   119
#define MAXO_   12
#define CONCAT_ 3325
#define E_      3328
#define TOTAL_  24696
#define HID_    1024
#define NREG_   300
#define NCLS_   180
#define EPS_    1e-5f
#define NSLOT_  128  // BN1 partial-stat slots
#define PSTR_   3328 // partial-stat stride

typedef __attribute__((ext_vector_type(8))) short bf16x8;
typedef __attribute__((ext_vector_type(4))) float f32x4;

static __device__ inline unsigned short f2bf_rne(float f) {
  unsigned u;
  __builtin_memcpy(&u, &f, 4);
  u += 0x7fff + ((u >> 16) & 1);     // round-nearest-even; inputs finite
  return (unsigned short)(u >> 16);
}

// ---------------- layout: ROI starts / reduced starts ----------------
__global__ void layout_kernel(int* __restrict__ starts, int* __restrict__ red_starts) {
  if (threadIdx.x == 0 && blockIdx.x == 0) {
    int s = 0, rs = 0;
    for (int r = 0; r < R_; ++r) {
      starts[r] = s;
      red_starts[r] = rs;
      s += 30 + (7 * r) % 90;
      rs += (r == 332) ? 8 : (8 + r % 5);
    }
  }
}

// ---------------- f32 -> bf16 cast (vectorized) ----------------
__global__ __launch_bounds__(256) void cast_bf16_kernel(const float* __restrict__ src,
                                                        unsigned short* __restrict__ dst, int n4) {
  int i = blockIdx.x * 256 + threadIdx.x;
  if (i >= n4) return;
  float4 v = ((const float4*)src)[i];
  ushort4 o;
  o.x = f2bf_rne(v.x); o.y = f2bf_rne(v.y); o.z = f2bf_rne(v.z); o.w = f2bf_rne(v.w);
  ((ushort4*)dst)[i] = o;
}

// ---------------- f32 -> bf16 transpose-cast: out[c][r] = in[r][c] ----------------
__global__ __launch_bounds__(256) void transpose_cast_kernel(
    const float* __restrict__ in, unsigned short* __restrict__ out, int Rows, int Cols) {
  __shared__ float tile[64][65];
  int r0 = blockIdx.y * 64, c0 = blockIdx.x * 64;
  int t = threadIdx.x;
  int ci = t & 63, ri0 = t >> 6;
  for (int ri = ri0; ri < 64; ri += 4)
    tile[ri][ci] = in[(size_t)(r0 + ri) * Cols + c0 + ci];
  __syncthreads();
  int rj = t & 63, i0 = t >> 6;
  for (int i = i0; i < 64; i += 4)
    out[(size_t)(c0 + i) * Rows + r0 + rj] = f2bf_rne(tile[rj][i]);
}

// ---------------- rowdot: out[j] = sum_k A[j,k]*v[k] + b[j] (f32 exact) ----------------
__global__ __launch_bounds__(256) void rowdot_kernel(
    const float* __restrict__ A, const float* __restrict__ v, const float* __restrict__ b,
    float* __restrict__ out, int N, int K) {
  int wid = threadIdx.x >> 6, lane = threadIdx.x & 63;
  int j = blockIdx.x * 4 + wid;
  if (j >= N) return;
  const float* row = A + (size_t)j * K;
  float s = 0.f;
  for (int k = lane; k < K; k += 64) s = fmaf(row[k], v[k], s);
  for (int o = 32; o; o >>= 1) s += __shfl_down(s, o);
  if (lane == 0) out[j] = s + b[j];
}

// ---------------- pack enc_W into MFMA A-frag order, alignment shift baked in ----------
__global__ __launch_bounds__(256) void pack_w_kernel(const float* __restrict__ enc_W,
                                                     const int* __restrict__ starts,
                                                     unsigned short* __restrict__ Wpk) {
  int r = blockIdx.x;
  int tid = threadIdx.x;
  int kc = tid >> 6, lane = tid & 63;
  int size = 30 + (7 * r) % 90;
  int s8 = starts[r] & 7;
  int oc = lane & 15;
  int k0 = kc * 32 + (lane >> 4) * 8;
  unsigned short o[8];
#pragma unroll
  for (int e = 0; e < 8; ++e) {
    int k = k0 + e - s8;
    float v = 0.f;
    if (oc < MAXO_ && k >= 0 && k < size) v = enc_W[((size_t)r * MAXO_ + oc) * MAXI_ + k];
    o[e] = f2bf_rne(v);
  }
  unsigned short* dst = Wpk + ((size_t)r * 4 + kc) * 512 + lane * 8;
  *(ushort4*)dst = *(ushort4*)&o[0];
  *(ushort4*)(dst + 4) = *(ushort4*)&o[4];
}

// ---------------- ragged encoder: direct global->VGPR frags, zero LDS/barriers ------
__global__ __launch_bounds__(256) void encode_kernel(
    const float* __restrict__ x, const unsigned short* __restrict__ Wpk,
    const float* __restrict__ enc_b, const int* __restrict__ starts,
    const int* __restrict__ red_starts,
    float* __restrict__ yT, float* __restrict__ pS1, float* __restrict__ pS2) {
  int r  = blockIdx.x;
  int bg = blockIdx.y;
  int tid = threadIdx.x;
  int wid = tid >> 6, lane = tid & 63;
  int lr = lane & 15, kg = lane >> 4;

  int size = 30 + (7 * r) % 90;
  int red  = (r == 332) ? 8 : (8 + r % 5);
  int st   = starts[r];
  int s8   = st & 7;
  int a0   = st & ~7;
  int rs   = red_starts[r];
  int nkc  = (s8 + size + 31) >> 5;
  int kmax = TOTAL_ - a0;

  bf16x8 wf[4];
  const unsigned short* wp = Wpk + (size_t)r * 2048 + lane * 8;
#pragma unroll
  for (int kc = 0; kc < 4; ++kc) wf[kc] = *(const bf16x8*)(wp + kc * 512);

  float bofs[4];
#pragma unroll
  for (int reg = 0; reg < 4; ++reg) {
    int oc = kg * 4 + reg;
    bofs[reg] = (oc < MAXO_) ? enc_b[r * MAXO_ + oc] : 0.f;
  }

  for (int t = 0; t < 4; ++t) {
    int b0 = bg * 256 + wid * 64 + t * 16;
    const float* xrow = x + (size_t)(b0 + lr) * TOTAL_ + a0;
    f32x4 acc = {0.f, 0.f, 0.f, 0.f};
#pragma unroll
    for (int kc = 0; kc < 4; ++kc) {
      if (kc < nkc) {
        int k0 = kc * 32 + kg * 8;
        if (k0 + 8 > kmax) k0 = kmax - 8;   // only all-zero-weight frags clamp
        float4 v0 = *(const float4*)(xrow + k0);
        float4 v1 = *(const float4*)(xrow + k0 + 4);
        bf16x8 xf;
        xf[0] = (short)f2bf_rne(v0.x); xf[1] = (short)f2bf_rne(v0.y);
        xf[2] = (short)f2bf_rne(v0.z); xf[3] = (short)f2bf_rne(v0.w);
        xf[4] = (short)f2bf_rne(v1.x); xf[5] = (short)f2bf_rne(v1.y);
        xf[6] = (short)f2bf_rne(v1.z); xf[7] = (short)f2bf_rne(v1.w);
        acc = __builtin_amdgcn_mfma_f32_16x16x32_bf16(wf[kc], xf, acc, 0, 0, 0);
      }
    }
    int slot = b0 >> 4;
#pragma unroll
    for (int reg = 0; reg < 4; ++reg) {
      int oc = kg * 4 + reg;
      if (oc < red) {
        float v = acc[reg] + bofs[reg];
        yT[(size_t)(rs + oc) * B_ + b0 + lr] = v;
        float a = v, s2 = v * v;
#pragma unroll
        for (int m = 1; m <= 8; m <<= 1) { a += __shfl_xor(a, m); s2 += __shfl_xor(s2, m); }
        if (lr == 0) {
          pS1[slot * PSTR_ + rs + oc] = a;
          pS2[slot * PSTR_ + rs + oc] = s2;
        }
      }
    }
  }
}

// ---------------- BN1 stats finalize ----------------
__global__ __launch_bounds__(256) void bn1_stats_kernel(const float* __restrict__ pS1,
                                                        const float* __restrict__ pS2,
                                                        float* __restrict__ mean, float* __restrict__ rstd) {
  int c = blockIdx.x * 256 + threadIdx.x;
  if (c >= CONCAT_) return;
  float s = 0.f, s2 = 0.f;
  for (int i = 0; i < NSLOT_; ++i) { s += pS1[i * PSTR_ + c]; s2 += pS2[i * PSTR_ + c]; }
  float m = s / B_;
  float v = s2 / B_ - m * m;
  mean[c] = m;
  rstd[c] = rsqrtf(v + EPS_);
}

// ---------------- BN1 + LeakyReLU(0.3) + transpose + pad-col write (bf16) ----------------
__global__ __launch_bounds__(256) void bn1_transpose_kernel(
    const float* __restrict__ yT, const float* __restrict__ mean, const float* __restrict__ rstd,
    const float* __restrict__ g, const float* __restrict__ bb, unsigned short* __restrict__ Y) {
  __shared__ float tile[64][65];
  int c0 = blockIdx.x * 64, b0 = blockIdx.y * 64;
  int t = threadIdx.x;
  int bi = t & 63, ci0 = t >> 6;
  for (int ci = ci0; ci < 64; ci += 4) {
    int c = c0 + ci;
    float v = 0.f;
    if (c < CONCAT_) {
      v = (yT[(size_t)c * B_ + b0 + bi] - mean[c]) * rstd[c] * g[c] + bb[c];
      v = v > 0.f ? v : 0.3f * v;
    }
    tile[ci][bi] = v;
  }
  __syncthreads();
  int cj = t & 63, bj0 = t >> 6;
  for (int bj = bj0; bj < 64; bj += 4) {
    int c = c0 + cj;
    if (c < CONCAT_)
      Y[(size_t)(b0 + bj) * E_ + c + 1] = f2bf_rne(tile[cj][bj]);
  }
}

__global__ __launch_bounds__(256) void pad_zero_kernel(unsigned short* __restrict__ Y) {
  int i = blockIdx.x * 256 + threadIdx.x;
  if (i >= B_ * 3) return;
  int b = i / 3, which = i % 3;
  int c = (which == 0) ? 0 : ((which == 1) ? 3326 : 3327);
  Y[(size_t)b * E_ + c] = 0;
}

// ---------------- 128x64-tile dbuf bf16 MFMA GEMM (+optional split-K) ----------------
template <int KS, bool OUT_BF16>
__global__ __launch_bounds__(256) void gemm_lds_kernel(
    const unsigned short* __restrict__ A, const unsigned short* __restrict__ W,
    const float* __restrict__ bias, float* __restrict__ Cf, unsigned short* __restrict__ Cb,
    int M, int N, int K) {
  __shared__ unsigned short a_lds[2][128 * 32];
  __shared__ unsigned short b_lds[2][64 * 32];
  int tid = threadIdx.x;
  int wid = tid >> 6, lane = tid & 63;
  int wr = wid >> 1, wc = wid & 1;
  int row0 = blockIdx.y * 128, col0 = blockIdx.x * 64;
  int lr = lane & 15, kg = lane >> 4;
  int Klocal = K / KS;
  int kbase = blockIdx.z * Klocal;

  int srow = tid >> 2, sk = (tid & 3) * 8;
  const unsigned short* aptr0 = A + (size_t)(row0 + srow) * K + kbase + sk;
  const unsigned short* aptr1 = aptr0 + (size_t)64 * K;
  int bcol = col0 + srow; if (bcol > N - 1) bcol = N - 1;
  const unsigned short* bptr = W + (size_t)bcol * K + kbase + sk;

  f32x4 acc[4][2] = {};
  int nk = Klocal >> 5;

#define STAGE_(buf, kc)                                                                         \
  do {                                                                                          \
    __builtin_amdgcn_global_load_lds((const __attribute__((address_space(1))) void*)(aptr0 + (kc)), \
        (__attribute__((address_space(3))) void*)(&a_lds[buf][wid * 512]), 16, 0, 0);           \
    __builtin_amdgcn_global_load_lds((const __attribute__((address_space(1))) void*)(aptr1 + (kc)), \
        (__attribute__((address_space(3))) void*)(&a_lds[buf][2048 + wid * 512]), 16, 0, 0);    \
    __builtin_amdgcn_global_load_lds((const __attribute__((address_space(1))) void*)(bptr + (kc)),  \
        (__attribute__((address_space(3))) void*)(&b_lds[buf][wid * 512]), 16, 0, 0);           \
  } while (0)

  STAGE_(0, 0);
  __syncthreads();
  int cur = 0;
  for (int t = 0; t < nk; ++t) {
    if (t + 1 < nk) STAGE_(cur ^ 1, (t + 1) * 32);
    bf16x8 a[4], b[2];
#pragma unroll
    for (int f = 0; f < 4; ++f)
      a[f] = *(const bf16x8*)&a_lds[cur][(wr * 64 + f * 16 + lr) * 32 + kg * 8];
#pragma unroll
    for (int f = 0; f < 2; ++f)
      b[f] = *(const bf16x8*)&b_lds[cur][(wc * 32 + f * 16 + lr) * 32 + kg * 8];
#pragma unroll
    for (int i = 0; i < 4; ++i)
#pragma unroll
      for (int j = 0; j < 2; ++j)
        acc[i][j] = __builtin_amdgcn_mfma_f32_16x16x32_bf16(a[i], b[j], acc[i][j], 0, 0, 0);
    __syncthreads();
    cur ^= 1;
  }
#undef STAGE_

#pragma unroll
  for (int j = 0; j < 2; ++j) {
    int ccol = col0 + wc * 32 + j * 16 + lr;
    if (ccol >= N) continue;
    float bv = (KS == 1 && bias) ? bias[ccol] : 0.f;
#pragma unroll
    for (int i = 0; i < 4; ++i) {
#pragma unroll
      for (int reg = 0; reg < 4; ++reg) {
        int crow = row0 + wr * 64 + i * 16 + kg * 4 + reg;
        float v = acc[i][j][reg] + bv;
        if (KS == 1) {
          if (OUT_BF16) Cb[(size_t)crow * N + ccol] = f2bf_rne(v);
          else          Cf[(size_t)crow * N + ccol] = v;
        } else {
          Cf[((size_t)blockIdx.z * M + crow) * N + ccol] = v;
        }
      }
    }
  }
}

// ---------------- split-K combine: sum partials + bias ----------------
__global__ __launch_bounds__(256) void combine_kernel(
    const float* __restrict__ part, const float* __restrict__ bias,
    float* __restrict__ out, int MN, int N, int KS) {
  int i = blockIdx.x * 256 + threadIdx.x;
  if (i >= MN) return;
  float s = bias[i % N];
  for (int z = 0; z < KS; ++z) s += part[(size_t)z * MN + i];
  out[i] = s;
}

// ---------------- BN2 stats over row-major Z ----------------
__global__ __launch_bounds__(256) void colstats_partial_kernel(
    const float* __restrict__ Z, float* __restrict__ pS, float* __restrict__ pS2,
    int M, int C, int rowsPerBlock) {
  int c = blockIdx.x * 256 + threadIdx.x;
  if (c >= C) return;
  int r0 = blockIdx.y * rowsPerBlock;
  float s = 0.f, s2 = 0.f;
  for (int r = r0; r < r0 + rowsPerBlock; ++r) {
    float v = Z[(size_t)r * C + c];
    s += v; s2 = fmaf(v, v, s2);
  }
  pS[blockIdx.y * C + c] = s;
  pS2[blockIdx.y * C + c] = s2;
}

__global__ __launch_bounds__(256) void colstats_final_kernel(
    const float* __restrict__ pS, const float* __restrict__ pS2,
    float* __restrict__ mean, float* __restrict__ rstd, int C, int nrb, int M) {
  int c = blockIdx.x * 256 + threadIdx.x;
  if (c >= C) return;
  float s = 0.f, s2 = 0.f;
  for (int i = 0; i < nrb; ++i) { s += pS[i * C + c]; s2 += pS2[i * C + c]; }
  float m = s / M;
  float v = s2 / M - m * m;
  mean[c] = m;
  rstd[c] = rsqrtf(v + EPS_);
}

// ---------------- BN2 apply + LeakyReLU(0.1) -> bf16 ----------------
__global__ __launch_bounds__(256) void bn2_apply_kernel(
    const float* __restrict__ Z, const float* __restrict__ mean, const float* __restrict__ rstd,
    const float* __restrict__ g, const float* __restrict__ bb, unsigned short* __restrict__ R) {
  int i = blockIdx.x * 256 + threadIdx.x;
  int c = i & (HID_ - 1);
  float v = (Z[i] - mean[c]) * rstd[c] * g[c] + bb[c];
  v = v > 0.f ? v : 0.1f * v;
  R[i] = f2bf_rne(v);
}

// ---------------- classifier: y_pred = softmax(reg @ Wc^T + bc) ----------------
__global__ __launch_bounds__(256) void classifier_kernel(
    const float* __restrict__ reg, const float* __restrict__ Wc, const float* __restrict__ bc,
    float* __restrict__ ypred) {
  int b = blockIdx.x;
  __shared__ __align__(16) float rrow[NREG_];
  __shared__ float sl[256];
  int tid = threadIdx.x;
  for (int i = tid; i < NREG_; i += 256) rrow[i] = reg[(size_t)b * NREG_ + i];
  __syncthreads();
  float s = -1e30f;
  if (tid < NCLS_) {
    const float* w = Wc + (size_t)tid * NREG_;
    float acc = 0.f;
    for (int k = 0; k < NREG_; k += 4) {
      float4 wv = *(const float4*)(w + k);
      float4 rv = *(const float4*)(&rrow[k]);
      acc = fmaf(wv.x, rv.x, acc); acc = fmaf(wv.y, rv.y, acc);
      acc = fmaf(wv.z, rv.z, acc); acc = fmaf(wv.w, rv.w, acc);
    }
    s = acc + bc[tid];
  }
  sl[tid] = s;
  __syncthreads();
  for (int o = 128; o > 0; o >>= 1) {
    if (tid < o) sl[tid] = fmaxf(sl[tid], sl[tid + o]);
    __syncthreads();
  }
  float mx = sl[0];
  __syncthreads();
  float e = (tid < NCLS_) ? __expf(s - mx) : 0.f;
  sl[tid] = e;
  __syncthreads();
  for (int o = 128; o > 0; o >>= 1) {
    if (tid < o) sl[tid] += sl[tid + o];
    __syncthreads();
  }
  if (tid < NCLS_) ypred[(size_t)b * NCLS_ + tid] = e / sl[0];
}

// ---------------- host orchestration ----------------
extern "C" void kernel_launch(void* const* d_in, const int* in_sizes, int n_in,
                              void* d_out, int out_size, void* d_ws, size_t ws_size,
                              hipStream_t stream) {
  const float* x     = (const float*)d_in[0];
  const float* enc_W = (const float*)d_in[1];
  const float* enc_b = (const float*)d_in[2];
  const float* bn1_g = (const float*)d_in[3];
  const float* bn1_b = (const float*)d_in[4];
  const float* Wqkv  = (const float*)d_in[5];
  const float* bqkv  = (const float*)d_in[6];
  const float* Wo    = (const float*)d_in[7];
  const float* bo    = (const float*)d_in[8];
  const float* W1    = (const float*)d_in[9];
  const float* b1    = (const float*)d_in[10];
  const float* bn2_g = (const float*)d_in[11];
  const float* bn2_b = (const float*)d_in[12];
  const float* W2    = (const float*)d_in[13];
  const float* b2    = (const float*)d_in[14];
  const float* Wc    = (const float*)d_in[15];
  const float* bc    = (const float*)d_in[16];

  char* ws = (char*)d_ws;
  size_t off = 0;
  auto alloc = [&](size_t bytes) -> void* {
    void* p = ws + off;
    off += (bytes + 255) & ~(size_t)255;
    return p;
  };

  float*          yT     = (float*)alloc((size_t)CONCAT_ * B_ * 4);       // reused for Z
  float*          pS1b   = (float*)alloc((size_t)NSLOT_ * PSTR_ * 4);
  float*          pS2b   = (float*)alloc((size_t)NSLOT_ * PSTR_ * 4);
  float*          mean1  = (float*)alloc(CONCAT_ * 4);
  float*          rstd1  = (float*)alloc(CONCAT_ * 4);
  unsigned short* Ybf    = (unsigned short*)alloc((size_t)B_ * E_ * 2);
  unsigned short* Rbf    = (unsigned short*)alloc((size_t)B_ * HID_ * 2);
  unsigned short* WoT_bf = (unsigned short*)alloc((size_t)E_ * E_ * 2);   // Wo^T  [e][j]
  unsigned short* WvT_bf = (unsigned short*)alloc((size_t)E_ * E_ * 2);   // Wv^T  [t][e]
  unsigned short* W1_bf  = (unsigned short*)alloc((size_t)HID_ * E_ * 2);
  unsigned short* W2_bf  = (unsigned short*)alloc((size_t)NREG_ * HID_ * 2);
  unsigned short* Wa_bf  = (unsigned short*)alloc((size_t)HID_ * E_ * 2); // W1*Wo
  unsigned short* Wb_bf  = (unsigned short*)alloc((size_t)HID_ * E_ * 2); // Wa*Wv
  unsigned short* Wpk    = (unsigned short*)alloc((size_t)R_ * 2048 * 2);
  float*          Cpart  = (float*)alloc((size_t)2 * B_ * HID_ * 4);
  float*          t1v    = (float*)alloc(E_ * 4);
  float*          zbv    = (float*)alloc(HID_ * 4);
  float*          partS  = (float*)alloc(16 * HID_ * 4);
  float*          partS2 = (float*)alloc(16 * HID_ * 4);
  float*          mean2  = (float*)alloc(HID_ * 4);
  float*          rstd2  = (float*)alloc(HID_ * 4);
  int*            starts = (int*)alloc(R_ * 4);
  int*            redst  = (int*)alloc(R_ * 4);

  float* Z = yT;   // yT dead after bn1_transpose

  layout_kernel<<<1, 1, 0, stream>>>(starts, redst);
  pack_w_kernel<<<R_, 256, 0, stream>>>(enc_W, starts, Wpk);

  // weight preprocessing
  int n4 = (HID_ * E_) / 4;
  cast_bf16_kernel<<<(n4 + 255) / 256, 256, 0, stream>>>(W1, W1_bf, n4);
  n4 = (NREG_ * HID_) / 4;
  cast_bf16_kernel<<<(n4 + 255) / 256, 256, 0, stream>>>(W2, W2_bf, n4);
  transpose_cast_kernel<<<dim3(E_ / 64, E_ / 64), 256, 0, stream>>>(Wo, WoT_bf, E_, E_);
  transpose_cast_kernel<<<dim3(E_ / 64, E_ / 64), 256, 0, stream>>>(
      Wqkv + (size_t)2 * E_ * E_, WvT_bf, E_, E_);

  // exact f32 fused bias: zb = W1*(Wo*bv + bo) + b1
  rowdot_kernel<<<E_ / 4, 256, 0, stream>>>(Wo, bqkv + 2 * E_, bo, t1v, E_, E_);
  rowdot_kernel<<<HID_ / 4, 256, 0, stream>>>(W1, t1v, b1, zbv, HID_, E_);

  // fused weights: Wa = W1*Wo  [1024 x 3328];  Wb = Wa*Wv  [1024 x 3328]
  gemm_lds_kernel<1, true><<<dim3(E_ / 64, HID_ / 128), 256, 0, stream>>>(
      W1_bf, WoT_bf, nullptr, nullptr, Wa_bf, HID_, E_, E_);
  gemm_lds_kernel<1, true><<<dim3(E_ / 64, HID_ / 128), 256, 0, stream>>>(
      Wa_bf, WvT_bf, nullptr, nullptr, Wb_bf, HID_, E_, E_);

  // encoder + BN1
  encode_kernel<<<dim3(R_, 8), 256, 0, stream>>>(
      x, Wpk, enc_b, starts, redst, yT, pS1b, pS2b);
  bn1_stats_kernel<<<(CONCAT_ + 255) / 256, 256, 0, stream>>>(pS1b, pS2b, mean1, rstd1);
  bn1_transpose_kernel<<<dim3((CONCAT_ + 63) / 64, B_ / 64), 256, 0, stream>>>(
      yT, mean1, rstd1, bn1_g, bn1_b, Ybf);
  pad_zero_kernel<<<(B_ * 3 + 255) / 256, 256, 0, stream>>>(Ybf);

  // Z = Y @ Wb^T + zb   (collapses V->O->Z chain; split-K=2: 512 blocks)
  gemm_lds_kernel<2, false><<<dim3(HID_ / 64, B_ / 128, 2), 256, 0, stream>>>(
      Ybf, Wb_bf, nullptr, Cpart, nullptr, B_, HID_, E_);
  combine_kernel<<<(B_ * HID_ + 255) / 256, 256, 0, stream>>>(
      Cpart, zbv, Z, B_ * HID_, HID_, 2);

  colstats_partial_kernel<<<dim3(HID_ / 256, 16), 256, 0, stream>>>(Z, partS, partS2, B_, HID_, B_ / 16);
  colstats_final_kernel<<<HID_ / 256, 256, 0, stream>>>(partS, partS2, mean2, rstd2, HID_, 16, B_);
  bn2_apply_kernel<<<(B_ * HID_) / 256, 256, 0, stream>>>(Z, mean2, rstd2, bn2_g, bn2_b, Rbf);

  // reg_out = R @ W2^T + b2  (split-K=4: 320 blocks)
  float* reg_out = (float*)d_out;
  gemm_lds_kernel<4, false><<<dim3((NREG_ + 63) / 64, B_ / 128, 4), 256, 0, stream>>>(
      Rbf, W2_bf, nullptr, Cpart, nullptr, B_, NREG_, HID_);
  combine_kernel<<<(B_ * NREG_ + 255) / 256, 256, 0, stream>>>(
      Cpart, b2, reg_out, B_ * NREG_, NREG_, 4);

  // y_pred = softmax(reg_out @ Wc^T + bc)
  classifier_kernel<<<B_, 256, 0, stream>>>(reg_out, Wc, bc, reg_out + (size_t)B_ * NREG_);
}

// Round 8
// 443.561 us; speedup vs baseline: 1.0489x; 1.0489x over previous
//
#include <hip/hip_runtime.h>
#include <hip/hip_bf16.h>

#define B_      2048
#define R_      333
#define MAXI_   119
#define MAXO_   12
#define CONCAT_ 3325
#define E_      3328
#define TOTAL_  24696
#define HID_    1024
#define NREG_   300
#define NCLS_   180
#define EPS_    1e-5f
#define NSLOT_  128  // BN1 partial-stat slots
#define PSTR_   3328 // partial-stat stride

typedef __attribute__((ext_vector_type(8))) short bf16x8;
typedef __attribute__((ext_vector_type(4))) float f32x4;

static __device__ inline unsigned short f2bf_rne(float f) {
  unsigned u;
  __builtin_memcpy(&u, &f, 4);
  u += 0x7fff + ((u >> 16) & 1);     // round-nearest-even; inputs finite
  return (unsigned short)(u >> 16);
}
static __device__ inline float bf2f(unsigned short s) {
  unsigned u = (unsigned)s << 16;
  float f;
  __builtin_memcpy(&f, &u, 4);
  return f;
}

// ---------------- layout: ROI starts / reduced starts ----------------
__global__ void layout_kernel(int* __restrict__ starts, int* __restrict__ red_starts) {
  if (threadIdx.x == 0 && blockIdx.x == 0) {
    int s = 0, rs = 0;
    for (int r = 0; r < R_; ++r) {
      starts[r] = s;
      red_starts[r] = rs;
      s += 30 + (7 * r) % 90;
      rs += (r == 332) ? 8 : (8 + r % 5);
    }
  }
}

// ---------------- f32 -> bf16 cast (vectorized) ----------------
__global__ __launch_bounds__(256) void cast_bf16_kernel(const float* __restrict__ src,
                                                        unsigned short* __restrict__ dst, int n4) {
  int i = blockIdx.x * 256 + threadIdx.x;
  if (i >= n4) return;
  float4 v = ((const float4*)src)[i];
  ushort4 o;
  o.x = f2bf_rne(v.x); o.y = f2bf_rne(v.y); o.z = f2bf_rne(v.z); o.w = f2bf_rne(v.w);
  ((ushort4*)dst)[i] = o;
}

// ---------------- dual f32 -> bf16 transpose-cast (z selects matrix) ----------------
__global__ __launch_bounds__(256) void transpose_cast2_kernel(
    const float* __restrict__ in0, const float* __restrict__ in1,
    unsigned short* __restrict__ out0, unsigned short* __restrict__ out1, int Rows, int Cols) {
  const float* in = blockIdx.z ? in1 : in0;
  unsigned short* out = blockIdx.z ? out1 : out0;
  __shared__ float tile[64][65];
  int r0 = blockIdx.y * 64, c0 = blockIdx.x * 64;
  int t = threadIdx.x;
  int ci = t & 63, ri0 = t >> 6;
  for (int ri = ri0; ri < 64; ri += 4)
    tile[ri][ci] = in[(size_t)(r0 + ri) * Cols + c0 + ci];
  __syncthreads();
  int rj = t & 63, i0 = t >> 6;
  for (int i = i0; i < 64; i += 4)
    out[(size_t)(c0 + i) * Rows + r0 + rj] = f2bf_rne(tile[rj][i]);
}

// ---------------- rowdot: out[j] = sum_k A[j,k]*v[k] + b[j] (f32 exact) ----------------
__global__ __launch_bounds__(256) void rowdot_kernel(
    const float* __restrict__ A, const float* __restrict__ v, const float* __restrict__ b,
    float* __restrict__ out, int N, int K) {
  int wid = threadIdx.x >> 6, lane = threadIdx.x & 63;
  int j = blockIdx.x * 4 + wid;
  if (j >= N) return;
  const float* row = A + (size_t)j * K;
  float s = 0.f;
  for (int k = lane; k < K; k += 64) s = fmaf(row[k], v[k], s);
  for (int o = 32; o; o >>= 1) s += __shfl_down(s, o);
  if (lane == 0) out[j] = s + b[j];
}

// ---------------- pack enc_W into MFMA A-frag order, alignment shift baked in ----------
__global__ __launch_bounds__(256) void pack_w_kernel(const float* __restrict__ enc_W,
                                                     const int* __restrict__ starts,
                                                     unsigned short* __restrict__ Wpk) {
  int r = blockIdx.x;
  int tid = threadIdx.x;
  int kc = tid >> 6, lane = tid & 63;
  int size = 30 + (7 * r) % 90;
  int s8 = starts[r] & 7;
  int oc = lane & 15;
  int k0 = kc * 32 + (lane >> 4) * 8;
  unsigned short o[8];
#pragma unroll
  for (int e = 0; e < 8; ++e) {
    int k = k0 + e - s8;
    float v = 0.f;
    if (oc < MAXO_ && k >= 0 && k < size) v = enc_W[((size_t)r * MAXO_ + oc) * MAXI_ + k];
    o[e] = f2bf_rne(v);
  }
  unsigned short* dst = Wpk + ((size_t)r * 4 + kc) * 512 + lane * 8;
  *(ushort4*)dst = *(ushort4*)&o[0];
  *(ushort4*)(dst + 4) = *(ushort4*)&o[4];
}

// ---------------- ragged encoder: direct global->VGPR frags, zero LDS/barriers ------
// yT written as bf16 (stats computed from exact f32 accumulators before rounding).
__global__ __launch_bounds__(256) void encode_kernel(
    const float* __restrict__ x, const unsigned short* __restrict__ Wpk,
    const float* __restrict__ enc_b, const int* __restrict__ starts,
    const int* __restrict__ red_starts,
    unsigned short* __restrict__ yT, float* __restrict__ pS1, float* __restrict__ pS2) {
  int r  = blockIdx.x;
  int bg = blockIdx.y;
  int tid = threadIdx.x;
  int wid = tid >> 6, lane = tid & 63;
  int lr = lane & 15, kg = lane >> 4;

  int size = 30 + (7 * r) % 90;
  int red  = (r == 332) ? 8 : (8 + r % 5);
  int st   = starts[r];
  int s8   = st & 7;
  int a0   = st & ~7;
  int rs   = red_starts[r];
  int nkc  = (s8 + size + 31) >> 5;
  int kmax = TOTAL_ - a0;

  bf16x8 wf[4];
  const unsigned short* wp = Wpk + (size_t)r * 2048 + lane * 8;
#pragma unroll
  for (int kc = 0; kc < 4; ++kc) wf[kc] = *(const bf16x8*)(wp + kc * 512);

  float bofs[4];
#pragma unroll
  for (int reg = 0; reg < 4; ++reg) {
    int oc = kg * 4 + reg;
    bofs[reg] = (oc < MAXO_) ? enc_b[r * MAXO_ + oc] : 0.f;
  }

  for (int t = 0; t < 4; ++t) {
    int b0 = bg * 256 + wid * 64 + t * 16;
    const float* xrow = x + (size_t)(b0 + lr) * TOTAL_ + a0;
    f32x4 acc = {0.f, 0.f, 0.f, 0.f};
#pragma unroll
    for (int kc = 0; kc < 4; ++kc) {
      if (kc < nkc) {
        int k0 = kc * 32 + kg * 8;
        if (k0 + 8 > kmax) k0 = kmax - 8;   // only all-zero-weight frags clamp
        float4 v0 = *(const float4*)(xrow + k0);
        float4 v1 = *(const float4*)(xrow + k0 + 4);
        bf16x8 xf;
        xf[0] = (short)f2bf_rne(v0.x); xf[1] = (short)f2bf_rne(v0.y);
        xf[2] = (short)f2bf_rne(v0.z); xf[3] = (short)f2bf_rne(v0.w);
        xf[4] = (short)f2bf_rne(v1.x); xf[5] = (short)f2bf_rne(v1.y);
        xf[6] = (short)f2bf_rne(v1.z); xf[7] = (short)f2bf_rne(v1.w);
        acc = __builtin_amdgcn_mfma_f32_16x16x32_bf16(wf[kc], xf, acc, 0, 0, 0);
      }
    }
    int slot = b0 >> 4;
#pragma unroll
    for (int reg = 0; reg < 4; ++reg) {
      int oc = kg * 4 + reg;
      if (oc < red) {
        float v = acc[reg] + bofs[reg];
        yT[(size_t)(rs + oc) * B_ + b0 + lr] = f2bf_rne(v);
        float a = v, s2 = v * v;
#pragma unroll
        for (int m = 1; m <= 8; m <<= 1) { a += __shfl_xor(a, m); s2 += __shfl_xor(s2, m); }
        if (lr == 0) {
          pS1[slot * PSTR_ + rs + oc] = a;
          pS2[slot * PSTR_ + rs + oc] = s2;
        }
      }
    }
  }
}

// ---------------- BN1 stats finalize ----------------
__global__ __launch_bounds__(256) void bn1_stats_kernel(const float* __restrict__ pS1,
                                                        const float* __restrict__ pS2,
                                                        float* __restrict__ mean, float* __restrict__ rstd) {
  int c = blockIdx.x * 256 + threadIdx.x;
  if (c >= CONCAT_) return;
  float s = 0.f, s2 = 0.f;
  for (int i = 0; i < NSLOT_; ++i) { s += pS1[i * PSTR_ + c]; s2 += pS2[i * PSTR_ + c]; }
  float m = s / B_;
  float v = s2 / B_ - m * m;
  mean[c] = m;
  rstd[c] = rsqrtf(v + EPS_);
}

// ---------------- BN1 + LeakyReLU(0.3) + transpose + FUSED pad (bf16 in/out) ------------
// grid.x covers ALL E_=3328 output cols; output col cc maps to feature c=cc-1;
// cc==0 and cc>=3326 write 0 (F.pad(1,2)).
__global__ __launch_bounds__(256) void bn1_transpose_kernel(
    const unsigned short* __restrict__ yT, const float* __restrict__ mean,
    const float* __restrict__ rstd, const float* __restrict__ g,
    const float* __restrict__ bb, unsigned short* __restrict__ Y) {
  __shared__ float tile[64][65];
  int cc0 = blockIdx.x * 64, b0 = blockIdx.y * 64;
  int t = threadIdx.x;
  int bi = t & 63, ci0 = t >> 6;
  for (int ci = ci0; ci < 64; ci += 4) {
    int c = cc0 + ci - 1;              // source feature
    float v = 0.f;
    if (c >= 0 && c < CONCAT_) {
      float f = bf2f(yT[(size_t)c * B_ + b0 + bi]);
      v = (f - mean[c]) * rstd[c] * g[c] + bb[c];
      v = v > 0.f ? v : 0.3f * v;
    }
    tile[ci][bi] = v;
  }
  __syncthreads();
  int cj = t & 63, bj0 = t >> 6;
  for (int bj = bj0; bj < 64; bj += 4)
    Y[(size_t)(b0 + bj) * E_ + cc0 + cj] = f2bf_rne(tile[cj][bj]);
}

// ---------------- 128x64-tile dbuf bf16 MFMA GEMM (+optional split-K) ----------------
template <int KS, bool OUT_BF16>
__global__ __launch_bounds__(256) void gemm_lds_kernel(
    const unsigned short* __restrict__ A, const unsigned short* __restrict__ W,
    const float* __restrict__ bias, float* __restrict__ Cf, unsigned short* __restrict__ Cb,
    int M, int N, int K) {
  __shared__ unsigned short a_lds[2][128 * 32];
  __shared__ unsigned short b_lds[2][64 * 32];
  int tid = threadIdx.x;
  int wid = tid >> 6, lane = tid & 63;
  int wr = wid >> 1, wc = wid & 1;
  int row0 = blockIdx.y * 128, col0 = blockIdx.x * 64;
  int lr = lane & 15, kg = lane >> 4;
  int Klocal = K / KS;
  int kbase = blockIdx.z * Klocal;

  int srow = tid >> 2, sk = (tid & 3) * 8;
  const unsigned short* aptr0 = A + (size_t)(row0 + srow) * K + kbase + sk;
  const unsigned short* aptr1 = aptr0 + (size_t)64 * K;
  int bcol = col0 + srow; if (bcol > N - 1) bcol = N - 1;
  const unsigned short* bptr = W + (size_t)bcol * K + kbase + sk;

  f32x4 acc[4][2] = {};
  int nk = Klocal >> 5;

#define STAGE_(buf, kc)                                                                         \
  do {                                                                                          \
    __builtin_amdgcn_global_load_lds((const __attribute__((address_space(1))) void*)(aptr0 + (kc)), \
        (__attribute__((address_space(3))) void*)(&a_lds[buf][wid * 512]), 16, 0, 0);           \
    __builtin_amdgcn_global_load_lds((const __attribute__((address_space(1))) void*)(aptr1 + (kc)), \
        (__attribute__((address_space(3))) void*)(&a_lds[buf][2048 + wid * 512]), 16, 0, 0);    \
    __builtin_amdgcn_global_load_lds((const __attribute__((address_space(1))) void*)(bptr + (kc)),  \
        (__attribute__((address_space(3))) void*)(&b_lds[buf][wid * 512]), 16, 0, 0);           \
  } while (0)

  STAGE_(0, 0);
  __syncthreads();
  int cur = 0;
  for (int t = 0; t < nk; ++t) {
    if (t + 1 < nk) STAGE_(cur ^ 1, (t + 1) * 32);
    bf16x8 a[4], b[2];
#pragma unroll
    for (int f = 0; f < 4; ++f)
      a[f] = *(const bf16x8*)&a_lds[cur][(wr * 64 + f * 16 + lr) * 32 + kg * 8];
#pragma unroll
    for (int f = 0; f < 2; ++f)
      b[f] = *(const bf16x8*)&b_lds[cur][(wc * 32 + f * 16 + lr) * 32 + kg * 8];
#pragma unroll
    for (int i = 0; i < 4; ++i)
#pragma unroll
      for (int j = 0; j < 2; ++j)
        acc[i][j] = __builtin_amdgcn_mfma_f32_16x16x32_bf16(a[i], b[j], acc[i][j], 0, 0, 0);
    __syncthreads();
    cur ^= 1;
  }
#undef STAGE_

#pragma unroll
  for (int j = 0; j < 2; ++j) {
    int ccol = col0 + wc * 32 + j * 16 + lr;
    if (ccol >= N) continue;
    float bv = (KS == 1 && bias) ? bias[ccol] : 0.f;
#pragma unroll
    for (int i = 0; i < 4; ++i) {
#pragma unroll
      for (int reg = 0; reg < 4; ++reg) {
        int crow = row0 + wr * 64 + i * 16 + kg * 4 + reg;
        float v = acc[i][j][reg] + bv;
        if (KS == 1) {
          if (OUT_BF16) Cb[(size_t)crow * N + ccol] = f2bf_rne(v);
          else          Cf[(size_t)crow * N + ccol] = v;
        } else {
          Cf[((size_t)blockIdx.z * M + crow) * N + ccol] = v;
        }
      }
    }
  }
}

// ---------------- split-K combine: sum partials + bias -> f32 or bf16 ----------------
template <bool OUT_BF16>
__global__ __launch_bounds__(256) void combine_kernel(
    const float* __restrict__ part, const float* __restrict__ bias,
    float* __restrict__ outf, unsigned short* __restrict__ outb, int MN, int N, int KS) {
  int i = blockIdx.x * 256 + threadIdx.x;
  if (i >= MN) return;
  float s = bias ? bias[i % N] : 0.f;
  for (int z = 0; z < KS; ++z) s += part[(size_t)z * MN + i];
  if (OUT_BF16) outb[i] = f2bf_rne(s);
  else          outf[i] = s;
}

// ---------------- BN2 stats over row-major Z ----------------
__global__ __launch_bounds__(256) void colstats_partial_kernel(
    const float* __restrict__ Z, float* __restrict__ pS, float* __restrict__ pS2,
    int M, int C, int rowsPerBlock) {
  int c = blockIdx.x * 256 + threadIdx.x;
  if (c >= C) return;
  int r0 = blockIdx.y * rowsPerBlock;
  float s = 0.f, s2 = 0.f;
  for (int r = r0; r < r0 + rowsPerBlock; ++r) {
    float v = Z[(size_t)r * C + c];
    s += v; s2 = fmaf(v, v, s2);
  }
  pS[blockIdx.y * C + c] = s;
  pS2[blockIdx.y * C + c] = s2;
}

__global__ __launch_bounds__(256) void colstats_final_kernel(
    const float* __restrict__ pS, const float* __restrict__ pS2,
    float* __restrict__ mean, float* __restrict__ rstd, int C, int nrb, int M) {
  int c = blockIdx.x * 256 + threadIdx.x;
  if (c >= C) return;
  float s = 0.f, s2 = 0.f;
  for (int i = 0; i < nrb; ++i) { s += pS[i * C + c]; s2 += pS2[i * C + c]; }
  float m = s / M;
  float v = s2 / M - m * m;
  mean[c] = m;
  rstd[c] = rsqrtf(v + EPS_);
}

// ---------------- BN2 apply + LeakyReLU(0.1) -> bf16 ----------------
__global__ __launch_bounds__(256) void bn2_apply_kernel(
    const float* __restrict__ Z, const float* __restrict__ mean, const float* __restrict__ rstd,
    const float* __restrict__ g, const float* __restrict__ bb, unsigned short* __restrict__ R) {
  int i = blockIdx.x * 256 + threadIdx.x;
  int c = i & (HID_ - 1);
  float v = (Z[i] - mean[c]) * rstd[c] * g[c] + bb[c];
  v = v > 0.f ? v : 0.1f * v;
  R[i] = f2bf_rne(v);
}

// ---------------- classifier: y_pred = softmax(reg @ Wc^T + bc) ----------------
__global__ __launch_bounds__(256) void classifier_kernel(
    const float* __restrict__ reg, const float* __restrict__ Wc, const float* __restrict__ bc,
    float* __restrict__ ypred) {
  int b = blockIdx.x;
  __shared__ __align__(16) float rrow[NREG_];
  __shared__ float sl[256];
  int tid = threadIdx.x;
  for (int i = tid; i < NREG_; i += 256) rrow[i] = reg[(size_t)b * NREG_ + i];
  __syncthreads();
  float s = -1e30f;
  if (tid < NCLS_) {
    const float* w = Wc + (size_t)tid * NREG_;
    float acc = 0.f;
    for (int k = 0; k < NREG_; k += 4) {
      float4 wv = *(const float4*)(w + k);
      float4 rv = *(const float4*)(&rrow[k]);
      acc = fmaf(wv.x, rv.x, acc); acc = fmaf(wv.y, rv.y, acc);
      acc = fmaf(wv.z, rv.z, acc); acc = fmaf(wv.w, rv.w, acc);
    }
    s = acc + bc[tid];
  }
  sl[tid] = s;
  __syncthreads();
  for (int o = 128; o > 0; o >>= 1) {
    if (tid < o) sl[tid] = fmaxf(sl[tid], sl[tid + o]);
    __syncthreads();
  }
  float mx = sl[0];
  __syncthreads();
  float e = (tid < NCLS_) ? __expf(s - mx) : 0.f;
  sl[tid] = e;
  __syncthreads();
  for (int o = 128; o > 0; o >>= 1) {
    if (tid < o) sl[tid] += sl[tid + o];
    __syncthreads();
  }
  if (tid < NCLS_) ypred[(size_t)b * NCLS_ + tid] = e / sl[0];
}

// ---------------- host orchestration ----------------
extern "C" void kernel_launch(void* const* d_in, const int* in_sizes, int n_in,
                              void* d_out, int out_size, void* d_ws, size_t ws_size,
                              hipStream_t stream) {
  const float* x     = (const float*)d_in[0];
  const float* enc_W = (const float*)d_in[1];
  const float* enc_b = (const float*)d_in[2];
  const float* bn1_g = (const float*)d_in[3];
  const float* bn1_b = (const float*)d_in[4];
  const float* Wqkv  = (const float*)d_in[5];
  const float* bqkv  = (const float*)d_in[6];
  const float* Wo    = (const float*)d_in[7];
  const float* bo    = (const float*)d_in[8];
  const float* W1    = (const float*)d_in[9];
  const float* b1    = (const float*)d_in[10];
  const float* bn2_g = (const float*)d_in[11];
  const float* bn2_b = (const float*)d_in[12];
  const float* W2    = (const float*)d_in[13];
  const float* b2    = (const float*)d_in[14];
  const float* Wc    = (const float*)d_in[15];
  const float* bc    = (const float*)d_in[16];

  char* ws = (char*)d_ws;
  size_t off = 0;
  auto alloc = [&](size_t bytes) -> void* {
    void* p = ws + off;
    off += (bytes + 255) & ~(size_t)255;
    return p;
  };

  unsigned short* yT     = (unsigned short*)alloc((size_t)CONCAT_ * B_ * 2); // bf16; reused for Z (f32, 8.4MB < 13.6MB)
  float*          pS1b   = (float*)alloc((size_t)NSLOT_ * PSTR_ * 4);
  float*          pS2b   = (float*)alloc((size_t)NSLOT_ * PSTR_ * 4);
  float*          mean1  = (float*)alloc(CONCAT_ * 4);
  float*          rstd1  = (float*)alloc(CONCAT_ * 4);
  unsigned short* Ybf    = (unsigned short*)alloc((size_t)B_ * E_ * 2);
  unsigned short* Rbf    = (unsigned short*)alloc((size_t)B_ * HID_ * 2);
  unsigned short* WoT_bf = (unsigned short*)alloc((size_t)E_ * E_ * 2);
  unsigned short* WvT_bf = (unsigned short*)alloc((size_t)E_ * E_ * 2);
  unsigned short* W1_bf  = (unsigned short*)alloc((size_t)HID_ * E_ * 2);
  unsigned short* W2_bf  = (unsigned short*)alloc((size_t)NREG_ * HID_ * 2);
  unsigned short* Wa_bf  = (unsigned short*)alloc((size_t)HID_ * E_ * 2);  // W1*Wo
  unsigned short* Wb_bf  = (unsigned short*)alloc((size_t)HID_ * E_ * 2);  // Wa*Wv
  unsigned short* Wpk    = (unsigned short*)alloc((size_t)R_ * 2048 * 2);
  float*          Cpart  = (float*)alloc((size_t)4 * B_ * HID_ * 4);       // split-K partials (max 33.5MB)
  float*          t1v    = (float*)alloc(E_ * 4);
  float*          zbv    = (float*)alloc(HID_ * 4);
  float*          partS  = (float*)alloc(16 * HID_ * 4);
  float*          partS2 = (float*)alloc(16 * HID_ * 4);
  float*          mean2  = (float*)alloc(HID_ * 4);
  float*          rstd2  = (float*)alloc(HID_ * 4);
  int*            starts = (int*)alloc(R_ * 4);
  int*            redst  = (int*)alloc(R_ * 4);

  float* Z = (float*)yT;   // yT dead after bn1_transpose

  layout_kernel<<<1, 1, 0, stream>>>(starts, redst);
  pack_w_kernel<<<R_, 256, 0, stream>>>(enc_W, starts, Wpk);

  // weight preprocessing
  int n4 = (HID_ * E_) / 4;
  cast_bf16_kernel<<<(n4 + 255) / 256, 256, 0, stream>>>(W1, W1_bf, n4);
  n4 = (NREG_ * HID_) / 4;
  cast_bf16_kernel<<<(n4 + 255) / 256, 256, 0, stream>>>(W2, W2_bf, n4);
  transpose_cast2_kernel<<<dim3(E_ / 64, E_ / 64, 2), 256, 0, stream>>>(
      Wo, Wqkv + (size_t)2 * E_ * E_, WoT_bf, WvT_bf, E_, E_);

  // exact f32 fused bias: zb = W1*(Wo*bv + bo) + b1
  rowdot_kernel<<<E_ / 4, 256, 0, stream>>>(Wo, bqkv + 2 * E_, bo, t1v, E_, E_);
  rowdot_kernel<<<HID_ / 4, 256, 0, stream>>>(W1, t1v, b1, zbv, HID_, E_);

  // fused weights: Wa = W1*Wo; Wb = Wa*Wv  (split-K=2 -> 832 blocks each)
  gemm_lds_kernel<2, false><<<dim3(E_ / 64, HID_ / 128, 2), 256, 0, stream>>>(
      W1_bf, WoT_bf, nullptr, Cpart, nullptr, HID_, E_, E_);
  combine_kernel<true><<<(HID_ * E_ + 255) / 256, 256, 0, stream>>>(
      Cpart, nullptr, nullptr, Wa_bf, HID_ * E_, E_, 2);
  gemm_lds_kernel<2, false><<<dim3(E_ / 64, HID_ / 128, 2), 256, 0, stream>>>(
      Wa_bf, WvT_bf, nullptr, Cpart, nullptr, HID_, E_, E_);
  combine_kernel<true><<<(HID_ * E_ + 255) / 256, 256, 0, stream>>>(
      Cpart, nullptr, nullptr, Wb_bf, HID_ * E_, E_, 2);

  // encoder + BN1 (+fused pad)
  encode_kernel<<<dim3(R_, 8), 256, 0, stream>>>(
      x, Wpk, enc_b, starts, redst, yT, pS1b, pS2b);
  bn1_stats_kernel<<<(CONCAT_ + 255) / 256, 256, 0, stream>>>(pS1b, pS2b, mean1, rstd1);
  bn1_transpose_kernel<<<dim3(E_ / 64, B_ / 64), 256, 0, stream>>>(
      yT, mean1, rstd1, bn1_g, bn1_b, Ybf);

  // Z = Y @ Wb^T + zb  (split-K=4 -> 1024 blocks)
  gemm_lds_kernel<4, false><<<dim3(HID_ / 64, B_ / 128, 4), 256, 0, stream>>>(
      Ybf, Wb_bf, nullptr, Cpart, nullptr, B_, HID_, E_);
  combine_kernel<false><<<(B_ * HID_ + 255) / 256, 256, 0, stream>>>(
      Cpart, zbv, Z, nullptr, B_ * HID_, HID_, 4);

  colstats_partial_kernel<<<dim3(HID_ / 256, 16), 256, 0, stream>>>(Z, partS, partS2, B_, HID_, B_ / 16);
  colstats_final_kernel<<<HID_ / 256, 256, 0, stream>>>(partS, partS2, mean2, rstd2, HID_, 16, B_);
  bn2_apply_kernel<<<(B_ * HID_) / 256, 256, 0, stream>>>(Z, mean2, rstd2, bn2_g, bn2_b, Rbf);

  // reg_out = R @ W2^T + b2  (split-K=4: 320 blocks)
  float* reg_out = (float*)d_out;
  gemm_lds_kernel<4, false><<<dim3((NREG_ + 63) / 64, B_ / 128, 4), 256, 0, stream>>>(
      Rbf, W2_bf, nullptr, Cpart, nullptr, B_, NREG_, HID_);
  combine_kernel<false><<<(B_ * NREG_ + 255) / 256, 256, 0, stream>>>(
      Cpart, b2, reg_out, nullptr, B_ * NREG_, NREG_, 4);

  // y_pred = softmax(reg_out @ Wc^T + bc)
  classifier_kernel<<<B_, 256, 0, stream>>>(reg_out, Wc, bc, reg_out + (size_t)B_ * NREG_);
}

// Round 9
// 360.409 us; speedup vs baseline: 1.2909x; 1.2307x over previous
//
#include <hip/hip_runtime.h>
#include <hip/hip_bf16.h>

#define B_      2048
#define R_      333
#define MAXI_   119
#define MAXO_   12
#define CONCAT_ 3325
#define E_      3328
#define TOTAL_  24696
#define HID_    1024
#define NREG_   300
#define NCLS_   180
#define EPS_    1e-5f
#define NSLOT_  128  // BN1 partial-stat slots
#define PSTR_   3328 // partial-stat stride
#define NS2_    128  // BN2 partial slots (2048/16)

typedef __attribute__((ext_vector_type(8))) short bf16x8;
typedef __attribute__((ext_vector_type(4))) float f32x4;

static __device__ inline unsigned short f2bf_rne(float f) {
  unsigned u;
  __builtin_memcpy(&u, &f, 4);
  u += 0x7fff + ((u >> 16) & 1);
  return (unsigned short)(u >> 16);
}
static __device__ inline float bf2f(unsigned short s) {
  unsigned u = (unsigned)s << 16;
  float f;
  __builtin_memcpy(&f, &u, 4);
  return f;
}

// ---------------- layout ----------------
__global__ void layout_kernel(int* __restrict__ starts, int* __restrict__ red_starts) {
  if (threadIdx.x == 0 && blockIdx.x == 0) {
    int s = 0, rs = 0;
    for (int r = 0; r < R_; ++r) {
      starts[r] = s;
      red_starts[r] = rs;
      s += 30 + (7 * r) % 90;
      rs += (r == 332) ? 8 : (8 + r % 5);
    }
  }
}

// ---------------- merged cast W1 + W2 (f32 -> bf16) ----------------
__global__ __launch_bounds__(256) void prep_cast_kernel(
    const float* __restrict__ W1, unsigned short* __restrict__ W1b,
    const float* __restrict__ W2, unsigned short* __restrict__ W2b) {
  const int n4a = HID_ * E_ / 4, n4b = NREG_ * HID_ / 4;
  int i = blockIdx.x * 256 + threadIdx.x;
  const float* src; unsigned short* dst; int idx;
  if (i < n4a) { src = W1; dst = W1b; idx = i; }
  else if (i < n4a + n4b) { src = W2; dst = W2b; idx = i - n4a; }
  else return;
  float4 v = ((const float4*)src)[idx];
  ushort4 o;
  o.x = f2bf_rne(v.x); o.y = f2bf_rne(v.y); o.z = f2bf_rne(v.z); o.w = f2bf_rne(v.w);
  ((ushort4*)dst)[idx] = o;
}

// ---------------- rowdot body: out[j] = A[j,:].v + b[j] (f32 exact) ----------------
__device__ __forceinline__ void rowdot_body(
    const float* __restrict__ A, const float* __restrict__ v, const float* __restrict__ b,
    float* __restrict__ out, int N, int K, int jb) {
  int wid = threadIdx.x >> 6, lane = threadIdx.x & 63;
  int j = jb * 4 + wid;
  if (j >= N) return;
  const float* row = A + (size_t)j * K;
  float s = 0.f;
  for (int k = lane; k < K; k += 64) s = fmaf(row[k], v[k], s);
  for (int o = 32; o; o >>= 1) s += __shfl_down(s, o);
  if (lane == 0) out[j] = s + b[j];
}

// ---------------- merged: dual transpose-cast (Wo^T, Wv^T) + rowdot1 (t1=Wo*bv+bo) ----
__global__ __launch_bounds__(256) void trans_rowdot_kernel(
    const float* __restrict__ Wo, const float* __restrict__ Wv,
    unsigned short* __restrict__ WoT, unsigned short* __restrict__ WvT,
    const float* __restrict__ bv, const float* __restrict__ bo, float* __restrict__ t1v) {
  __shared__ float tile[64][65];
  int bid = blockIdx.x;
  const int NT = (E_ / 64) * (E_ / 64);      // 2704 per matrix
  if (bid < 2 * NT) {
    int z = bid / NT, rem = bid % NT;
    const float* in = z ? Wv : Wo;
    unsigned short* out = z ? WvT : WoT;
    int c0 = (rem % 52) * 64, r0 = (rem / 52) * 64;
    int t = threadIdx.x;
    int ci = t & 63, ri0 = t >> 6;
    for (int ri = ri0; ri < 64; ri += 4)
      tile[ri][ci] = in[(size_t)(r0 + ri) * E_ + c0 + ci];
    __syncthreads();
    int rj = t & 63, i0 = t >> 6;
    for (int i = i0; i < 64; i += 4)
      out[(size_t)(c0 + i) * E_ + r0 + rj] = f2bf_rne(tile[rj][i]);
  } else {
    rowdot_body(Wo, bv, bo, t1v, E_, E_, bid - 2 * NT);
  }
}

// ---------------- pack enc_W (alignment shift baked in) body ----------------
__device__ __forceinline__ void pack_w_body(const float* __restrict__ enc_W,
                                            const int* __restrict__ starts,
                                            unsigned short* __restrict__ Wpk, int r) {
  int tid = threadIdx.x;
  int kc = tid >> 6, lane = tid & 63;
  int size = 30 + (7 * r) % 90;
  int s8 = starts[r] & 7;
  int oc = lane & 15;
  int k0 = kc * 32 + (lane >> 4) * 8;
  unsigned short o[8];
#pragma unroll
  for (int e = 0; e < 8; ++e) {
    int k = k0 + e - s8;
    float v = 0.f;
    if (oc < MAXO_ && k >= 0 && k < size) v = enc_W[((size_t)r * MAXO_ + oc) * MAXI_ + k];
    o[e] = f2bf_rne(v);
  }
  unsigned short* dst = Wpk + ((size_t)r * 4 + kc) * 512 + lane * 8;
  *(ushort4*)dst = *(ushort4*)&o[0];
  *(ushort4*)(dst + 4) = *(ushort4*)&o[4];
}

// ---------------- merged: pack_w + rowdot2 (zb = W1*t1 + b1) ----------------
__global__ __launch_bounds__(256) void packw_rowdot_kernel(
    const float* __restrict__ enc_W, const int* __restrict__ starts,
    unsigned short* __restrict__ Wpk,
    const float* __restrict__ W1, const float* __restrict__ t1v,
    const float* __restrict__ b1, float* __restrict__ zbv) {
  int bid = blockIdx.x;
  if (bid < R_) pack_w_body(enc_W, starts, Wpk, bid);
  else          rowdot_body(W1, t1v, b1, zbv, HID_, E_, bid - R_);
}

// ---------------- encoder body: direct global->VGPR frags, zero LDS/barriers --------
__device__ __forceinline__ void encode_body(
    const float* __restrict__ x, const unsigned short* __restrict__ Wpk,
    const float* __restrict__ enc_b, const int* __restrict__ starts,
    const int* __restrict__ red_starts,
    unsigned short* __restrict__ yT, float* __restrict__ pS1, float* __restrict__ pS2,
    int r, int bg) {
  int tid = threadIdx.x;
  int wid = tid >> 6, lane = tid & 63;
  int lr = lane & 15, kg = lane >> 4;

  int size = 30 + (7 * r) % 90;
  int red  = (r == 332) ? 8 : (8 + r % 5);
  int st   = starts[r];
  int s8   = st & 7;
  int a0   = st & ~7;
  int rs   = red_starts[r];
  int nkc  = (s8 + size + 31) >> 5;
  int kmax = TOTAL_ - a0;

  bf16x8 wf[4];
  const unsigned short* wp = Wpk + (size_t)r * 2048 + lane * 8;
#pragma unroll
  for (int kc = 0; kc < 4; ++kc) wf[kc] = *(const bf16x8*)(wp + kc * 512);

  float bofs[4];
#pragma unroll
  for (int reg = 0; reg < 4; ++reg) {
    int oc = kg * 4 + reg;
    bofs[reg] = (oc < MAXO_) ? enc_b[r * MAXO_ + oc] : 0.f;
  }

  for (int t = 0; t < 4; ++t) {
    int b0 = bg * 256 + wid * 64 + t * 16;
    const float* xrow = x + (size_t)(b0 + lr) * TOTAL_ + a0;
    f32x4 acc = {0.f, 0.f, 0.f, 0.f};
#pragma unroll
    for (int kc = 0; kc < 4; ++kc) {
      if (kc < nkc) {
        int k0 = kc * 32 + kg * 8;
        if (k0 + 8 > kmax) k0 = kmax - 8;   // only all-zero-weight frags clamp
        float4 v0 = *(const float4*)(xrow + k0);
        float4 v1 = *(const float4*)(xrow + k0 + 4);
        bf16x8 xf;
        xf[0] = (short)f2bf_rne(v0.x); xf[1] = (short)f2bf_rne(v0.y);
        xf[2] = (short)f2bf_rne(v0.z); xf[3] = (short)f2bf_rne(v0.w);
        xf[4] = (short)f2bf_rne(v1.x); xf[5] = (short)f2bf_rne(v1.y);
        xf[6] = (short)f2bf_rne(v1.z); xf[7] = (short)f2bf_rne(v1.w);
        acc = __builtin_amdgcn_mfma_f32_16x16x32_bf16(wf[kc], xf, acc, 0, 0, 0);
      }
    }
    int slot = b0 >> 4;
#pragma unroll
    for (int reg = 0; reg < 4; ++reg) {
      int oc = kg * 4 + reg;
      if (oc < red) {
        float v = acc[reg] + bofs[reg];
        yT[(size_t)(rs + oc) * B_ + b0 + lr] = f2bf_rne(v);
        float a = v, s2 = v * v;
#pragma unroll
        for (int m = 1; m <= 8; m <<= 1) { a += __shfl_xor(a, m); s2 += __shfl_xor(s2, m); }
        if (lr == 0) {
          pS1[slot * PSTR_ + rs + oc] = a;
          pS2[slot * PSTR_ + rs + oc] = s2;
        }
      }
    }
  }
}

// ---------------- GEMM body: 128x64 tile, BK=32, dbuf 2-phase, optional split-K ------
template <int KS, bool OUT_BF16>
__device__ __forceinline__ void gemm_body(
    const unsigned short* __restrict__ A, const unsigned short* __restrict__ W,
    const float* __restrict__ bias, float* __restrict__ Cf, unsigned short* __restrict__ Cb,
    int M, int N, int K, int bx, int by, int bz,
    unsigned short* a_lds, unsigned short* b_lds) {
  int tid = threadIdx.x;
  int wid = tid >> 6, lane = tid & 63;
  int wr = wid >> 1, wc = wid & 1;
  int row0 = by * 128, col0 = bx * 64;
  int lr = lane & 15, kg = lane >> 4;
  int Klocal = K / KS;
  int kbase = bz * Klocal;

  int srow = tid >> 2, sk = (tid & 3) * 8;
  const unsigned short* aptr0 = A + (size_t)(row0 + srow) * K + kbase + sk;
  const unsigned short* aptr1 = aptr0 + (size_t)64 * K;
  int bcol = col0 + srow; if (bcol > N - 1) bcol = N - 1;
  const unsigned short* bptr = W + (size_t)bcol * K + kbase + sk;

  f32x4 acc[4][2] = {};
  int nk = Klocal >> 5;

#define STAGE_(buf, kc)                                                                             \
  do {                                                                                              \
    __builtin_amdgcn_global_load_lds((const __attribute__((address_space(1))) void*)(aptr0 + (kc)), \
        (__attribute__((address_space(3))) void*)(a_lds + (buf) * 4096 + wid * 512), 16, 0, 0);     \
    __builtin_amdgcn_global_load_lds((const __attribute__((address_space(1))) void*)(aptr1 + (kc)), \
        (__attribute__((address_space(3))) void*)(a_lds + (buf) * 4096 + 2048 + wid * 512), 16, 0, 0); \
    __builtin_amdgcn_global_load_lds((const __attribute__((address_space(1))) void*)(bptr + (kc)),  \
        (__attribute__((address_space(3))) void*)(b_lds + (buf) * 2048 + wid * 512), 16, 0, 0);     \
  } while (0)

  STAGE_(0, 0);
  __syncthreads();
  int cur = 0;
  for (int t = 0; t < nk; ++t) {
    if (t + 1 < nk) STAGE_(cur ^ 1, (t + 1) * 32);
    bf16x8 a[4], b[2];
#pragma unroll
    for (int f = 0; f < 4; ++f)
      a[f] = *(const bf16x8*)(a_lds + cur * 4096 + (wr * 64 + f * 16 + lr) * 32 + kg * 8);
#pragma unroll
    for (int f = 0; f < 2; ++f)
      b[f] = *(const bf16x8*)(b_lds + cur * 2048 + (wc * 32 + f * 16 + lr) * 32 + kg * 8);
#pragma unroll
    for (int i = 0; i < 4; ++i)
#pragma unroll
      for (int j = 0; j < 2; ++j)
        acc[i][j] = __builtin_amdgcn_mfma_f32_16x16x32_bf16(a[i], b[j], acc[i][j], 0, 0, 0);
    __syncthreads();
    cur ^= 1;
  }
#undef STAGE_

#pragma unroll
  for (int j = 0; j < 2; ++j) {
    int ccol = col0 + wc * 32 + j * 16 + lr;
    if (ccol >= N) continue;
    float bv = (KS == 1 && bias) ? bias[ccol] : 0.f;
#pragma unroll
    for (int i = 0; i < 4; ++i) {
#pragma unroll
      for (int reg = 0; reg < 4; ++reg) {
        int crow = row0 + wr * 64 + i * 16 + kg * 4 + reg;
        float v = acc[i][j][reg] + bv;
        if (KS == 1) {
          if (OUT_BF16) Cb[(size_t)crow * N + ccol] = f2bf_rne(v);
          else          Cf[(size_t)crow * N + ccol] = v;
        } else {
          Cf[((size_t)bz * M + crow) * N + ccol] = v;
        }
      }
    }
  }
}

// ---------------- merged: Wa gemm (KS=1 -> bf16) + encoder ----------------
#define ENC_NB_ (R_ * 8)
#define WA_NB_  ((E_ / 64) * (HID_ / 128))   // 416
__global__ __launch_bounds__(256) void enc_wa_kernel(
    const float* __restrict__ x, const unsigned short* __restrict__ Wpk,
    const float* __restrict__ enc_b, const int* __restrict__ starts,
    const int* __restrict__ red_starts,
    unsigned short* __restrict__ yT, float* __restrict__ pS1, float* __restrict__ pS2,
    const unsigned short* __restrict__ W1b, const unsigned short* __restrict__ WoT,
    unsigned short* __restrict__ Wa_bf) {
  __shared__ __align__(16) unsigned short smem[12288];   // 24 KB: a_lds(16K)+b_lds(8K)
  int bid = blockIdx.x;
  if (bid < WA_NB_) {
    gemm_body<1, true>(W1b, WoT, nullptr, nullptr, Wa_bf, HID_, E_, E_,
                       bid % 52, bid / 52, 0, smem, smem + 8192);
  } else {
    int eb = bid - WA_NB_;
    encode_body(x, Wpk, enc_b, starts, red_starts, yT, pS1, pS2, eb >> 3, eb & 7);
  }
}

// ---------------- BN1 stats finalize ----------------
__global__ __launch_bounds__(256) void bn1_stats_kernel(const float* __restrict__ pS1,
                                                        const float* __restrict__ pS2,
                                                        float* __restrict__ mean, float* __restrict__ rstd) {
  int c = blockIdx.x * 256 + threadIdx.x;
  if (c >= CONCAT_) return;
  float s = 0.f, s2 = 0.f;
  for (int i = 0; i < NSLOT_; ++i) { s += pS1[i * PSTR_ + c]; s2 += pS2[i * PSTR_ + c]; }
  float m = s / B_;
  float v = s2 / B_ - m * m;
  mean[c] = m;
  rstd[c] = rsqrtf(v + EPS_);
}

// ---------------- merged: Wb gemm (KS=2) + bn1_transpose(+pad) ----------------
#define TR_NB_ ((E_ / 64) * (B_ / 64))       // 1664
#define WB_NB_ ((E_ / 64) * (HID_ / 128) * 2) // 832
__global__ __launch_bounds__(256) void trans_wb_kernel(
    const unsigned short* __restrict__ yT, const float* __restrict__ mean,
    const float* __restrict__ rstd, const float* __restrict__ g,
    const float* __restrict__ bb, unsigned short* __restrict__ Y,
    const unsigned short* __restrict__ Wa_bf, const unsigned short* __restrict__ WvT,
    float* __restrict__ Cpart) {
  __shared__ __align__(16) unsigned short smem[12288];
  int bid = blockIdx.x;
  if (bid < WB_NB_) {
    gemm_body<2, false>(Wa_bf, WvT, nullptr, Cpart, nullptr, HID_, E_, E_,
                        bid % 52, (bid / 52) & 7, bid / 416, smem, smem + 8192);
  } else {
    int tb = bid - WB_NB_;
    int cc0 = (tb % 52) * 64, b0 = (tb / 52) * 64;
    float (*tile)[65] = (float(*)[65])smem;
    int t = threadIdx.x;
    int bi = t & 63, ci0 = t >> 6;
    for (int ci = ci0; ci < 64; ci += 4) {
      int c = cc0 + ci - 1;              // F.pad(1,2): output col cc -> feature cc-1
      float v = 0.f;
      if (c >= 0 && c < CONCAT_) {
        float f = bf2f(yT[(size_t)c * B_ + b0 + bi]);
        v = (f - mean[c]) * rstd[c] * g[c] + bb[c];
        v = v > 0.f ? v : 0.3f * v;
      }
      tile[ci][bi] = v;
    }
    __syncthreads();
    int cj = t & 63, bj0 = t >> 6;
    for (int bj = bj0; bj < 64; bj += 4)
      Y[(size_t)(b0 + bj) * E_ + cc0 + cj] = f2bf_rne(tile[cj][bj]);
  }
}

// ---------------- combine Wb (2 slices -> bf16) ----------------
__global__ __launch_bounds__(256) void combine_wb_kernel(const float* __restrict__ part,
                                                         unsigned short* __restrict__ out) {
  const int MN = HID_ * E_;
  int i = blockIdx.x * 256 + threadIdx.x;
  if (i >= MN) return;
  out[i] = f2bf_rne(part[i] + part[(size_t)MN + i]);
}

// ---------------- standalone GEMM kernel wrapper ----------------
template <int KS, bool OUT_BF16>
__global__ __launch_bounds__(256) void gemm_kernel(
    const unsigned short* __restrict__ A, const unsigned short* __restrict__ W,
    const float* __restrict__ bias, float* __restrict__ Cf, unsigned short* __restrict__ Cb,
    int M, int N, int K) {
  __shared__ __align__(16) unsigned short smem[12288];
  gemm_body<KS, OUT_BF16>(A, W, bias, Cf, Cb, M, N, K,
                          blockIdx.x, blockIdx.y, blockIdx.z, smem, smem + 8192);
}

// ---------------- fused: Z combine (4 slices + zb) + BN2 partial stats ----------------
__global__ __launch_bounds__(256) void combZ_stats_kernel(
    const float* __restrict__ Cpart, const float* __restrict__ zb,
    float* __restrict__ Z, float* __restrict__ pS, float* __restrict__ pS2) {
  int c = blockIdx.x * 256 + threadIdx.x;    // grid.x = 4 -> c in [0,1024)
  int ry = blockIdx.y;                        // 128 groups of 16 rows
  float zbc = zb[c];
  float s1 = 0.f, s2 = 0.f;
  for (int r = ry * 16; r < ry * 16 + 16; ++r) {
    float v = zbc;
#pragma unroll
    for (int z = 0; z < 4; ++z) v += Cpart[((size_t)z * B_ + r) * HID_ + c];
    Z[(size_t)r * HID_ + c] = v;
    s1 += v; s2 = fmaf(v, v, s2);
  }
  pS[ry * HID_ + c] = s1;
  pS2[ry * HID_ + c] = s2;
}

__global__ __launch_bounds__(256) void colstats_final_kernel(
    const float* __restrict__ pS, const float* __restrict__ pS2,
    float* __restrict__ mean, float* __restrict__ rstd) {
  int c = blockIdx.x * 256 + threadIdx.x;
  if (c >= HID_) return;
  float s = 0.f, s2 = 0.f;
  for (int i = 0; i < NS2_; ++i) { s += pS[i * HID_ + c]; s2 += pS2[i * HID_ + c]; }
  float m = s / B_;
  float v = s2 / B_ - m * m;
  mean[c] = m;
  rstd[c] = rsqrtf(v + EPS_);
}

// ---------------- BN2 apply + LeakyReLU(0.1) -> bf16 ----------------
__global__ __launch_bounds__(256) void bn2_apply_kernel(
    const float* __restrict__ Z, const float* __restrict__ mean, const float* __restrict__ rstd,
    const float* __restrict__ g, const float* __restrict__ bb, unsigned short* __restrict__ R) {
  int i = blockIdx.x * 256 + threadIdx.x;
  int c = i & (HID_ - 1);
  float v = (Z[i] - mean[c]) * rstd[c] * g[c] + bb[c];
  v = v > 0.f ? v : 0.1f * v;
  R[i] = f2bf_rne(v);
}

// ---------------- classifier with fused W2 split-K combine ----------------
__global__ __launch_bounds__(256) void classifier_kernel(
    const float* __restrict__ Cpart, const float* __restrict__ b2,
    const float* __restrict__ Wc, const float* __restrict__ bc,
    float* __restrict__ reg_out, float* __restrict__ ypred) {
  int b = blockIdx.x;
  __shared__ __align__(16) float rrow[NREG_];
  __shared__ float sl[256];
  int tid = threadIdx.x;
  for (int i = tid; i < NREG_; i += 256) {
    float s = b2[i];
#pragma unroll
    for (int z = 0; z < 4; ++z) s += Cpart[((size_t)z * B_ + b) * NREG_ + i];
    rrow[i] = s;
    reg_out[(size_t)b * NREG_ + i] = s;
  }
  __syncthreads();
  float s = -1e30f;
  if (tid < NCLS_) {
    const float* w = Wc + (size_t)tid * NREG_;
    float acc = 0.f;
    for (int k = 0; k < NREG_; k += 4) {
      float4 wv = *(const float4*)(w + k);
      float4 rv = *(const float4*)(&rrow[k]);
      acc = fmaf(wv.x, rv.x, acc); acc = fmaf(wv.y, rv.y, acc);
      acc = fmaf(wv.z, rv.z, acc); acc = fmaf(wv.w, rv.w, acc);
    }
    s = acc + bc[tid];
  }
  sl[tid] = s;
  __syncthreads();
  for (int o = 128; o > 0; o >>= 1) {
    if (tid < o) sl[tid] = fmaxf(sl[tid], sl[tid + o]);
    __syncthreads();
  }
  float mx = sl[0];
  __syncthreads();
  float e = (tid < NCLS_) ? __expf(s - mx) : 0.f;
  sl[tid] = e;
  __syncthreads();
  for (int o = 128; o > 0; o >>= 1) {
    if (tid < o) sl[tid] += sl[tid + o];
    __syncthreads();
  }
  if (tid < NCLS_) ypred[(size_t)b * NCLS_ + tid] = e / sl[0];
}

// ---------------- host orchestration ----------------
extern "C" void kernel_launch(void* const* d_in, const int* in_sizes, int n_in,
                              void* d_out, int out_size, void* d_ws, size_t ws_size,
                              hipStream_t stream) {
  const float* x     = (const float*)d_in[0];
  const float* enc_W = (const float*)d_in[1];
  const float* enc_b = (const float*)d_in[2];
  const float* bn1_g = (const float*)d_in[3];
  const float* bn1_b = (const float*)d_in[4];
  const float* Wqkv  = (const float*)d_in[5];
  const float* bqkv  = (const float*)d_in[6];
  const float* Wo    = (const float*)d_in[7];
  const float* bo    = (const float*)d_in[8];
  const float* W1    = (const float*)d_in[9];
  const float* b1    = (const float*)d_in[10];
  const float* bn2_g = (const float*)d_in[11];
  const float* bn2_b = (const float*)d_in[12];
  const float* W2    = (const float*)d_in[13];
  const float* b2    = (const float*)d_in[14];
  const float* Wc    = (const float*)d_in[15];
  const float* bc    = (const float*)d_in[16];

  char* ws = (char*)d_ws;
  size_t off = 0;
  auto alloc = [&](size_t bytes) -> void* {
    void* p = ws + off;
    off += (bytes + 255) & ~(size_t)255;
    return p;
  };

  unsigned short* yT     = (unsigned short*)alloc((size_t)CONCAT_ * B_ * 2); // bf16; reused for Z(f32)
  float*          pS1b   = (float*)alloc((size_t)NSLOT_ * PSTR_ * 4);
  float*          pS2b   = (float*)alloc((size_t)NSLOT_ * PSTR_ * 4);
  float*          mean1  = (float*)alloc(CONCAT_ * 4);
  float*          rstd1  = (float*)alloc(CONCAT_ * 4);
  unsigned short* Ybf    = (unsigned short*)alloc((size_t)B_ * E_ * 2);
  unsigned short* Rbf    = (unsigned short*)alloc((size_t)B_ * HID_ * 2);
  unsigned short* WoT_bf = (unsigned short*)alloc((size_t)E_ * E_ * 2);
  unsigned short* WvT_bf = (unsigned short*)alloc((size_t)E_ * E_ * 2);
  unsigned short* W1_bf  = (unsigned short*)alloc((size_t)HID_ * E_ * 2);
  unsigned short* W2_bf  = (unsigned short*)alloc((size_t)NREG_ * HID_ * 2);
  unsigned short* Wa_bf  = (unsigned short*)alloc((size_t)HID_ * E_ * 2);
  unsigned short* Wb_bf  = (unsigned short*)alloc((size_t)HID_ * E_ * 2);
  unsigned short* Wpk    = (unsigned short*)alloc((size_t)R_ * 2048 * 2);
  float*          Cpart  = (float*)alloc((size_t)4 * B_ * HID_ * 4);        // 33.5 MB (covers all uses)
  float*          t1v    = (float*)alloc(E_ * 4);
  float*          zbv    = (float*)alloc(HID_ * 4);
  float*          partS  = (float*)alloc((size_t)NS2_ * HID_ * 4);
  float*          partS2 = (float*)alloc((size_t)NS2_ * HID_ * 4);
  float*          mean2  = (float*)alloc(HID_ * 4);
  float*          rstd2  = (float*)alloc(HID_ * 4);
  int*            starts = (int*)alloc(R_ * 4);
  int*            redst  = (int*)alloc(R_ * 4);

  float* Z = (float*)yT;   // yT dead after trans_wb

  // 1. layout
  layout_kernel<<<1, 1, 0, stream>>>(starts, redst);
  // 2. casts W1+W2
  {
    int nb = (HID_ * E_ / 4 + NREG_ * HID_ / 4 + 255) / 256;
    prep_cast_kernel<<<nb, 256, 0, stream>>>(W1, W1_bf, W2, W2_bf);
  }
  // 3. Wo^T, Wv^T transpose-casts + t1 = Wo*bv + bo
  trans_rowdot_kernel<<<2 * 2704 + E_ / 4, 256, 0, stream>>>(
      Wo, Wqkv + (size_t)2 * E_ * E_, WoT_bf, WvT_bf, bqkv + 2 * E_, bo, t1v);
  // 4. pack enc_W + zb = W1*t1 + b1
  packw_rowdot_kernel<<<R_ + HID_ / 4, 256, 0, stream>>>(
      enc_W, starts, Wpk, W1, t1v, b1, zbv);
  // 5. MERGED: Wa = W1*Wo (KS1 -> bf16 direct)  ||  encoder (+BN1 partials)
  enc_wa_kernel<<<WA_NB_ + ENC_NB_, 256, 0, stream>>>(
      x, Wpk, enc_b, starts, redst, yT, pS1b, pS2b, W1_bf, WoT_bf, Wa_bf);
  // 6. BN1 stats finalize
  bn1_stats_kernel<<<(CONCAT_ + 255) / 256, 256, 0, stream>>>(pS1b, pS2b, mean1, rstd1);
  // 7. MERGED: Wb = Wa*Wv (KS2 -> Cpart)  ||  BN1 apply + transpose + pad -> Y
  trans_wb_kernel<<<WB_NB_ + TR_NB_, 256, 0, stream>>>(
      yT, mean1, rstd1, bn1_g, bn1_b, Ybf, Wa_bf, WvT_bf, Cpart);
  // 8. combine Wb -> bf16
  combine_wb_kernel<<<(HID_ * E_ + 255) / 256, 256, 0, stream>>>(Cpart, Wb_bf);
  // 9. Z = Y @ Wb^T (KS=4 -> Cpart)
  gemm_kernel<4, false><<<dim3(HID_ / 64, B_ / 128, 4), 256, 0, stream>>>(
      Ybf, Wb_bf, nullptr, Cpart, nullptr, B_, HID_, E_);
  // 10. Z combine + zb bias + BN2 partial stats
  combZ_stats_kernel<<<dim3(HID_ / 256, NS2_), 256, 0, stream>>>(Cpart, zbv, Z, partS, partS2);
  // 11. BN2 stats finalize
  colstats_final_kernel<<<(HID_ + 255) / 256, 256, 0, stream>>>(partS, partS2, mean2, rstd2);
  // 12. BN2 apply -> bf16
  bn2_apply_kernel<<<(B_ * HID_) / 256, 256, 0, stream>>>(Z, mean2, rstd2, bn2_g, bn2_b, Rbf);
  // 13. reg partials: R @ W2^T (KS=4 -> Cpart)
  gemm_kernel<4, false><<<dim3((NREG_ + 63) / 64, B_ / 128, 4), 256, 0, stream>>>(
      Rbf, W2_bf, nullptr, Cpart, nullptr, B_, NREG_, HID_);
  // 14. classifier (fused W2 combine + b2) -> reg_out, y_pred
  float* reg_out = (float*)d_out;
  classifier_kernel<<<B_, 256, 0, stream>>>(
      Cpart, b2, Wc, bc, reg_out, reg_out + (size_t)B_ * NREG_);
}

// Round 10
// 336.880 us; speedup vs baseline: 1.3810x; 1.0698x over previous
//
#include <hip/hip_runtime.h>
#include <hip/hip_bf16.h>

#define B_      2048
#define R_      333
#define MAXI_   119
#define MAXO_   12
#define CONCAT_ 3325
#define E_      3328
#define TOTAL_  24696
#define HID_    1024
#define NREG_   300
#define NCLS_   180
#define EPS_    1e-5f
#define NSLOT_  128
#define PSTR_   3328
#define NS2_    128

typedef __attribute__((ext_vector_type(8))) short bf16x8;
typedef __attribute__((ext_vector_type(4))) float f32x4;

static __device__ inline unsigned short f2bf_rne(float f) {
  unsigned u;
  __builtin_memcpy(&u, &f, 4);
  u += 0x7fff + ((u >> 16) & 1);
  return (unsigned short)(u >> 16);
}
static __device__ inline float bf2f(unsigned short s) {
  unsigned u = (unsigned)s << 16;
  float f;
  __builtin_memcpy(&f, &u, 4);
  return f;
}

// ---------------- layout ----------------
__global__ void layout_kernel(int* __restrict__ starts, int* __restrict__ red_starts) {
  if (threadIdx.x == 0 && blockIdx.x == 0) {
    int s = 0, rs = 0;
    for (int r = 0; r < R_; ++r) {
      starts[r] = s;
      red_starts[r] = rs;
      s += 30 + (7 * r) % 90;
      rs += (r == 332) ? 8 : (8 + r % 5);
    }
  }
}

// ---------------- rowdot body: out[j] = A[j,:].v + b[j] (f32 exact) ----------------
__device__ __forceinline__ void rowdot_body(
    const float* __restrict__ A, const float* __restrict__ v, const float* __restrict__ b,
    float* __restrict__ out, int N, int K, int jb) {
  int wid = threadIdx.x >> 6, lane = threadIdx.x & 63;
  int j = jb * 4 + wid;
  if (j >= N) return;
  const float* row = A + (size_t)j * K;
  float s = 0.f;
  for (int k = lane; k < K; k += 64) s = fmaf(row[k], v[k], s);
  for (int o = 32; o; o >>= 1) s += __shfl_down(s, o);
  if (lane == 0) out[j] = s + b[j];
}

// ---------------- pack enc_W body (alignment shift baked in) ----------------
__device__ __forceinline__ void pack_w_body(const float* __restrict__ enc_W,
                                            const int* __restrict__ starts,
                                            unsigned short* __restrict__ Wpk, int r) {
  int tid = threadIdx.x;
  int kc = tid >> 6, lane = tid & 63;
  int size = 30 + (7 * r) % 90;
  int s8 = starts[r] & 7;
  int oc = lane & 15;
  int k0 = kc * 32 + (lane >> 4) * 8;
  unsigned short o[8];
#pragma unroll
  for (int e = 0; e < 8; ++e) {
    int k = k0 + e - s8;
    float v = 0.f;
    if (oc < MAXO_ && k >= 0 && k < size) v = enc_W[((size_t)r * MAXO_ + oc) * MAXI_ + k];
    o[e] = f2bf_rne(v);
  }
  unsigned short* dst = Wpk + ((size_t)r * 4 + kc) * 512 + lane * 8;
  *(ushort4*)dst = *(ushort4*)&o[0];
  *(ushort4*)(dst + 4) = *(ushort4*)&o[4];
}

// ---------------- P1: transposes(Wo,Wv) || casts(W1,W2) || rowdot1 || pack_w ----------
#define NTR_   ((E_ / 64) * (E_ / 64))                        // 2704 per matrix
#define NC4A_  (HID_ * E_ / 4)
#define NC4B_  (NREG_ * HID_ / 4)
#define NCAST_ ((NC4A_ + NC4B_ + 255) / 256)                  // 3628
__global__ __launch_bounds__(256) void prep_kernel(
    const float* __restrict__ Wo, const float* __restrict__ Wv,
    unsigned short* __restrict__ WoT, unsigned short* __restrict__ WvT,
    const float* __restrict__ W1, unsigned short* __restrict__ W1b,
    const float* __restrict__ W2, unsigned short* __restrict__ W2b,
    const float* __restrict__ bv, const float* __restrict__ bo, float* __restrict__ t1v,
    const float* __restrict__ enc_W, const int* __restrict__ starts,
    unsigned short* __restrict__ Wpk) {
  __shared__ float tile[64][65];
  int bid = blockIdx.x;
  if (bid < 2 * NTR_) {
    int z = bid / NTR_, rem = bid % NTR_;
    const float* in = z ? Wv : Wo;
    unsigned short* out = z ? WvT : WoT;
    int c0 = (rem % 52) * 64, r0 = (rem / 52) * 64;
    int t = threadIdx.x;
    int ci = t & 63, ri0 = t >> 6;
    for (int ri = ri0; ri < 64; ri += 4)
      tile[ri][ci] = in[(size_t)(r0 + ri) * E_ + c0 + ci];
    __syncthreads();
    int rj = t & 63, i0 = t >> 6;
    for (int i = i0; i < 64; i += 4)
      out[(size_t)(c0 + i) * E_ + r0 + rj] = f2bf_rne(tile[rj][i]);
  } else if (bid < 2 * NTR_ + NCAST_) {
    int i = (bid - 2 * NTR_) * 256 + threadIdx.x;
    const float* src; unsigned short* dst; int idx;
    if (i < NC4A_) { src = W1; dst = W1b; idx = i; }
    else if (i < NC4A_ + NC4B_) { src = W2; dst = W2b; idx = i - NC4A_; }
    else return;
    float4 v = ((const float4*)src)[idx];
    ushort4 o;
    o.x = f2bf_rne(v.x); o.y = f2bf_rne(v.y); o.z = f2bf_rne(v.z); o.w = f2bf_rne(v.w);
    ((ushort4*)dst)[idx] = o;
  } else if (bid < 2 * NTR_ + NCAST_ + E_ / 4) {
    rowdot_body(Wo, bv, bo, t1v, E_, E_, bid - 2 * NTR_ - NCAST_);
  } else {
    pack_w_body(enc_W, starts, Wpk, bid - 2 * NTR_ - NCAST_ - E_ / 4);
  }
}

// ---------------- encoder body: 2-tile pipelined, direct global->VGPR, zero LDS -------
__device__ __forceinline__ void encode_body(
    const float* __restrict__ x, const unsigned short* __restrict__ Wpk,
    const float* __restrict__ enc_b, const int* __restrict__ starts,
    const int* __restrict__ red_starts,
    unsigned short* __restrict__ yT, float* __restrict__ pS1, float* __restrict__ pS2,
    int r, int bg) {
  int tid = threadIdx.x;
  int wid = tid >> 6, lane = tid & 63;
  int lr = lane & 15, kg = lane >> 4;

  int size = 30 + (7 * r) % 90;
  int red  = (r == 332) ? 8 : (8 + r % 5);
  int st   = starts[r];
  int s8   = st & 7;
  int a0   = st & ~7;
  int rs   = red_starts[r];
  int nkc  = (s8 + size + 31) >> 5;
  int kmax = TOTAL_ - a0;

  bf16x8 wf[4];
  const unsigned short* wp = Wpk + (size_t)r * 2048 + lane * 8;
#pragma unroll
  for (int kc = 0; kc < 4; ++kc) wf[kc] = *(const bf16x8*)(wp + kc * 512);

  float bofs[4];
#pragma unroll
  for (int reg = 0; reg < 4; ++reg) {
    int oc = kg * 4 + reg;
    bofs[reg] = (oc < MAXO_) ? enc_b[r * MAXO_ + oc] : 0.f;
  }

  int ks[4];
#pragma unroll
  for (int kc = 0; kc < 4; ++kc) {
    int k0 = kc * 32 + kg * 8;
    if (k0 + 8 > kmax) k0 = kmax - 8;   // only all-zero-weight frags clamp
    ks[kc] = k0;
  }

  for (int tp = 0; tp < 2; ++tp) {      // pairs of 16-row tiles; 16 loads in flight
    int b0a = bg * 256 + wid * 64 + tp * 32;
    int b0b = b0a + 16;
    const float* xra = x + (size_t)(b0a + lr) * TOTAL_ + a0;
    const float* xrb = x + (size_t)(b0b + lr) * TOTAL_ + a0;
    float4 va[4][2], vb[4][2];
#pragma unroll
    for (int kc = 0; kc < 4; ++kc) {
      if (kc < nkc) {
        va[kc][0] = *(const float4*)(xra + ks[kc]);
        va[kc][1] = *(const float4*)(xra + ks[kc] + 4);
        vb[kc][0] = *(const float4*)(xrb + ks[kc]);
        vb[kc][1] = *(const float4*)(xrb + ks[kc] + 4);
      }
    }
    f32x4 acca = {0.f, 0.f, 0.f, 0.f}, accb = {0.f, 0.f, 0.f, 0.f};
#pragma unroll
    for (int kc = 0; kc < 4; ++kc) {
      if (kc < nkc) {
        bf16x8 xfa, xfb;
#pragma unroll
        for (int e = 0; e < 4; ++e) {
          xfa[e]     = (short)f2bf_rne(va[kc][0][e]);
          xfa[e + 4] = (short)f2bf_rne(va[kc][1][e]);
          xfb[e]     = (short)f2bf_rne(vb[kc][0][e]);
          xfb[e + 4] = (short)f2bf_rne(vb[kc][1][e]);
        }
        acca = __builtin_amdgcn_mfma_f32_16x16x32_bf16(wf[kc], xfa, acca, 0, 0, 0);
        accb = __builtin_amdgcn_mfma_f32_16x16x32_bf16(wf[kc], xfb, accb, 0, 0, 0);
      }
    }
#pragma unroll
    for (int half = 0; half < 2; ++half) {
      int b0 = half ? b0b : b0a;
      f32x4 acc = half ? accb : acca;
      int slot = b0 >> 4;
#pragma unroll
      for (int reg = 0; reg < 4; ++reg) {
        int oc = kg * 4 + reg;
        if (oc < red) {
          float v = acc[reg] + bofs[reg];
          yT[(size_t)(rs + oc) * B_ + b0 + lr] = f2bf_rne(v);
          float a = v, s2 = v * v;
#pragma unroll
          for (int m = 1; m <= 8; m <<= 1) { a += __shfl_xor(a, m); s2 += __shfl_xor(s2, m); }
          if (lr == 0) {
            pS1[slot * PSTR_ + rs + oc] = a;
            pS2[slot * PSTR_ + rs + oc] = s2;
          }
        }
      }
    }
  }
}

// ---------------- GEMM body: 128x128 tile, BK=32, dbuf 2-phase, optional split-K ------
// 4 waves 2x2; wave = 64x64 = 4x4 frags; 16 MFMA + 8 ds_read_b128 per wave-K-step.
template <int KS, bool OUT_BF16>
__device__ __forceinline__ void gemm_body(
    const unsigned short* __restrict__ A, const unsigned short* __restrict__ W,
    float* __restrict__ Cf, unsigned short* __restrict__ Cb,
    int M, int N, int K, int bx, int by, int bz, unsigned short* smem) {
  unsigned short* a_lds = smem;            // 2 x 4096 elem (8KB each)
  unsigned short* b_lds = smem + 8192;
  int tid = threadIdx.x;
  int wid = tid >> 6, lane = tid & 63;
  int wr = wid >> 1, wc = wid & 1;
  int row0 = by * 128, col0 = bx * 128;
  int lr = lane & 15, kg = lane >> 4;
  int Klocal = K / KS;
  int kbase = bz * Klocal;

  int srow = tid >> 2, sk = (tid & 3) * 8;
  const unsigned short* aptr0 = A + (size_t)(row0 + srow) * K + kbase + sk;
  const unsigned short* aptr1 = aptr0 + (size_t)64 * K;
  int bcol0 = col0 + srow;      if (bcol0 > N - 1) bcol0 = N - 1;
  int bcol1 = col0 + 64 + srow; if (bcol1 > N - 1) bcol1 = N - 1;
  const unsigned short* bptr0 = W + (size_t)bcol0 * K + kbase + sk;
  const unsigned short* bptr1 = W + (size_t)bcol1 * K + kbase + sk;

  f32x4 acc[4][4] = {};
  int nk = Klocal >> 5;

#define STAGE_(buf, kc)                                                                             \
  do {                                                                                              \
    __builtin_amdgcn_global_load_lds((const __attribute__((address_space(1))) void*)(aptr0 + (kc)), \
        (__attribute__((address_space(3))) void*)(a_lds + (buf) * 4096 + wid * 512), 16, 0, 0);     \
    __builtin_amdgcn_global_load_lds((const __attribute__((address_space(1))) void*)(aptr1 + (kc)), \
        (__attribute__((address_space(3))) void*)(a_lds + (buf) * 4096 + 2048 + wid * 512), 16, 0, 0); \
    __builtin_amdgcn_global_load_lds((const __attribute__((address_space(1))) void*)(bptr0 + (kc)), \
        (__attribute__((address_space(3))) void*)(b_lds + (buf) * 4096 + wid * 512), 16, 0, 0);     \
    __builtin_amdgcn_global_load_lds((const __attribute__((address_space(1))) void*)(bptr1 + (kc)), \
        (__attribute__((address_space(3))) void*)(b_lds + (buf) * 4096 + 2048 + wid * 512), 16, 0, 0); \
  } while (0)

  STAGE_(0, 0);
  __syncthreads();
  int cur = 0;
  for (int t = 0; t < nk; ++t) {
    if (t + 1 < nk) STAGE_(cur ^ 1, (t + 1) * 32);
    bf16x8 a[4], b[4];
#pragma unroll
    for (int f = 0; f < 4; ++f) {
      a[f] = *(const bf16x8*)(a_lds + cur * 4096 + (wr * 64 + f * 16 + lr) * 32 + kg * 8);
      b[f] = *(const bf16x8*)(b_lds + cur * 4096 + (wc * 64 + f * 16 + lr) * 32 + kg * 8);
    }
#pragma unroll
    for (int i = 0; i < 4; ++i)
#pragma unroll
      for (int j = 0; j < 4; ++j)
        acc[i][j] = __builtin_amdgcn_mfma_f32_16x16x32_bf16(a[i], b[j], acc[i][j], 0, 0, 0);
    __syncthreads();
    cur ^= 1;
  }
#undef STAGE_

#pragma unroll
  for (int j = 0; j < 4; ++j) {
    int ccol = col0 + wc * 64 + j * 16 + lr;
    if (ccol >= N) continue;
#pragma unroll
    for (int i = 0; i < 4; ++i) {
#pragma unroll
      for (int reg = 0; reg < 4; ++reg) {
        int crow = row0 + wr * 64 + i * 16 + kg * 4 + reg;
        float v = acc[i][j][reg];
        if (KS == 1) {
          if (OUT_BF16) Cb[(size_t)crow * N + ccol] = f2bf_rne(v);
          else          Cf[(size_t)crow * N + ccol] = v;
        } else {
          Cf[((size_t)bz * M + crow) * N + ccol] = v;
        }
      }
    }
  }
}

// ---------------- merged: Wa gemm (208) + encoder (2664) + rowdot2 (256) ----------------
#define WA_NB_  ((E_ / 128) * (HID_ / 128))   // 208
#define ENC_NB_ (R_ * 8)                       // 2664
__global__ __launch_bounds__(256) void enc_wa_kernel(
    const float* __restrict__ x, const unsigned short* __restrict__ Wpk,
    const float* __restrict__ enc_b, const int* __restrict__ starts,
    const int* __restrict__ red_starts,
    unsigned short* __restrict__ yT, float* __restrict__ pS1, float* __restrict__ pS2,
    const unsigned short* __restrict__ W1b, const unsigned short* __restrict__ WoT,
    unsigned short* __restrict__ Wa_bf,
    const float* __restrict__ W1, const float* __restrict__ t1v,
    const float* __restrict__ b1, float* __restrict__ zbv) {
  __shared__ __align__(16) unsigned short smem[16384];   // 32 KB
  int bid = blockIdx.x;
  if (bid < WA_NB_) {
    gemm_body<1, true>(W1b, WoT, nullptr, Wa_bf, HID_, E_, E_,
                       bid % (E_ / 128), bid / (E_ / 128), 0, smem);
  } else if (bid < WA_NB_ + ENC_NB_) {
    int eb = bid - WA_NB_;
    encode_body(x, Wpk, enc_b, starts, red_starts, yT, pS1, pS2, eb >> 3, eb & 7);
  } else {
    rowdot_body(W1, t1v, b1, zbv, HID_, E_, bid - WA_NB_ - ENC_NB_);
  }
}

// ---------------- BN1 stats finalize ----------------
__global__ __launch_bounds__(256) void bn1_stats_kernel(const float* __restrict__ pS1,
                                                        const float* __restrict__ pS2,
                                                        float* __restrict__ mean, float* __restrict__ rstd) {
  int c = blockIdx.x * 256 + threadIdx.x;
  if (c >= CONCAT_) return;
  float s = 0.f, s2 = 0.f;
  for (int i = 0; i < NSLOT_; ++i) { s += pS1[i * PSTR_ + c]; s2 += pS2[i * PSTR_ + c]; }
  float m = s / B_;
  float v = s2 / B_ - m * m;
  mean[c] = m;
  rstd[c] = rsqrtf(v + EPS_);
}

// ---------------- merged: Wb gemm (KS=2, 416) + bn1_transpose(+pad) (1664) ------------
#define WB_NB_ ((E_ / 128) * (HID_ / 128) * 2)  // 416
#define TR_NB_ ((E_ / 64) * (B_ / 64))          // 1664
__global__ __launch_bounds__(256) void trans_wb_kernel(
    const unsigned short* __restrict__ yT, const float* __restrict__ mean,
    const float* __restrict__ rstd, const float* __restrict__ g,
    const float* __restrict__ bb, unsigned short* __restrict__ Y,
    const unsigned short* __restrict__ Wa_bf, const unsigned short* __restrict__ WvT,
    float* __restrict__ Cpart) {
  __shared__ __align__(16) unsigned short smem[16384];
  int bid = blockIdx.x;
  if (bid < WB_NB_) {
    int z = bid / (WB_NB_ / 2), rem = bid % (WB_NB_ / 2);
    gemm_body<2, false>(Wa_bf, WvT, Cpart, nullptr, HID_, E_, E_,
                        rem % (E_ / 128), rem / (E_ / 128), z, smem);
  } else {
    int tb = bid - WB_NB_;
    int cc0 = (tb % 52) * 64, b0 = (tb / 52) * 64;
    float (*tile)[65] = (float(*)[65])smem;
    int t = threadIdx.x;
    int bi = t & 63, ci0 = t >> 6;
    for (int ci = ci0; ci < 64; ci += 4) {
      int c = cc0 + ci - 1;              // F.pad(1,2): output col cc -> feature cc-1
      float v = 0.f;
      if (c >= 0 && c < CONCAT_) {
        float f = bf2f(yT[(size_t)c * B_ + b0 + bi]);
        v = (f - mean[c]) * rstd[c] * g[c] + bb[c];
        v = v > 0.f ? v : 0.3f * v;
      }
      tile[ci][bi] = v;
    }
    __syncthreads();
    int cj = t & 63, bj0 = t >> 6;
    for (int bj = bj0; bj < 64; bj += 4)
      Y[(size_t)(b0 + bj) * E_ + cc0 + cj] = f2bf_rne(tile[cj][bj]);
  }
}

// ---------------- combine Wb (2 slices -> bf16) ----------------
__global__ __launch_bounds__(256) void combine_wb_kernel(const float* __restrict__ part,
                                                         unsigned short* __restrict__ out) {
  const int MN = HID_ * E_;
  int i = blockIdx.x * 256 + threadIdx.x;
  if (i >= MN) return;
  out[i] = f2bf_rne(part[i] + part[(size_t)MN + i]);
}

// ---------------- standalone GEMM wrapper ----------------
template <int KS, bool OUT_BF16>
__global__ __launch_bounds__(256) void gemm_kernel(
    const unsigned short* __restrict__ A, const unsigned short* __restrict__ W,
    float* __restrict__ Cf, unsigned short* __restrict__ Cb, int M, int N, int K) {
  __shared__ __align__(16) unsigned short smem[16384];
  gemm_body<KS, OUT_BF16>(A, W, Cf, Cb, M, N, K, blockIdx.x, blockIdx.y, blockIdx.z, smem);
}

// ---------------- fused: Z combine (4 slices + zb) + BN2 partial stats ----------------
__global__ __launch_bounds__(256) void combZ_stats_kernel(
    const float* __restrict__ Cpart, const float* __restrict__ zb,
    float* __restrict__ Z, float* __restrict__ pS, float* __restrict__ pS2) {
  int c = blockIdx.x * 256 + threadIdx.x;
  int ry = blockIdx.y;
  float zbc = zb[c];
  float s1 = 0.f, s2 = 0.f;
  for (int r = ry * 16; r < ry * 16 + 16; ++r) {
    float v = zbc;
#pragma unroll
    for (int z = 0; z < 4; ++z) v += Cpart[((size_t)z * B_ + r) * HID_ + c];
    Z[(size_t)r * HID_ + c] = v;
    s1 += v; s2 = fmaf(v, v, s2);
  }
  pS[ry * HID_ + c] = s1;
  pS2[ry * HID_ + c] = s2;
}

__global__ __launch_bounds__(256) void colstats_final_kernel(
    const float* __restrict__ pS, const float* __restrict__ pS2,
    float* __restrict__ mean, float* __restrict__ rstd) {
  int c = blockIdx.x * 256 + threadIdx.x;
  if (c >= HID_) return;
  float s = 0.f, s2 = 0.f;
  for (int i = 0; i < NS2_; ++i) { s += pS[i * HID_ + c]; s2 += pS2[i * HID_ + c]; }
  float m = s / B_;
  float v = s2 / B_ - m * m;
  mean[c] = m;
  rstd[c] = rsqrtf(v + EPS_);
}

// ---------------- BN2 apply + LeakyReLU(0.1) -> bf16 ----------------
__global__ __launch_bounds__(256) void bn2_apply_kernel(
    const float* __restrict__ Z, const float* __restrict__ mean, const float* __restrict__ rstd,
    const float* __restrict__ g, const float* __restrict__ bb, unsigned short* __restrict__ R) {
  int i = blockIdx.x * 256 + threadIdx.x;
  int c = i & (HID_ - 1);
  float v = (Z[i] - mean[c]) * rstd[c] * g[c] + bb[c];
  v = v > 0.f ? v : 0.1f * v;
  R[i] = f2bf_rne(v);
}

// ---------------- classifier with fused W2 split-K combine ----------------
__global__ __launch_bounds__(256) void classifier_kernel(
    const float* __restrict__ Cpart, const float* __restrict__ b2,
    const float* __restrict__ Wc, const float* __restrict__ bc,
    float* __restrict__ reg_out, float* __restrict__ ypred) {
  int b = blockIdx.x;
  __shared__ __align__(16) float rrow[NREG_];
  __shared__ float sl[256];
  int tid = threadIdx.x;
  for (int i = tid; i < NREG_; i += 256) {
    float s = b2[i];
#pragma unroll
    for (int z = 0; z < 4; ++z) s += Cpart[((size_t)z * B_ + b) * NREG_ + i];
    rrow[i] = s;
    reg_out[(size_t)b * NREG_ + i] = s;
  }
  __syncthreads();
  float s = -1e30f;
  if (tid < NCLS_) {
    const float* w = Wc + (size_t)tid * NREG_;
    float acc = 0.f;
    for (int k = 0; k < NREG_; k += 4) {
      float4 wv = *(const float4*)(w + k);
      float4 rv = *(const float4*)(&rrow[k]);
      acc = fmaf(wv.x, rv.x, acc); acc = fmaf(wv.y, rv.y, acc);
      acc = fmaf(wv.z, rv.z, acc); acc = fmaf(wv.w, rv.w, acc);
    }
    s = acc + bc[tid];
  }
  sl[tid] = s;
  __syncthreads();
  for (int o = 128; o > 0; o >>= 1) {
    if (tid < o) sl[tid] = fmaxf(sl[tid], sl[tid + o]);
    __syncthreads();
  }
  float mx = sl[0];
  __syncthreads();
  float e = (tid < NCLS_) ? __expf(s - mx) : 0.f;
  sl[tid] = e;
  __syncthreads();
  for (int o = 128; o > 0; o >>= 1) {
    if (tid < o) sl[tid] += sl[tid + o];
    __syncthreads();
  }
  if (tid < NCLS_) ypred[(size_t)b * NCLS_ + tid] = e / sl[0];
}

// ---------------- host orchestration ----------------
extern "C" void kernel_launch(void* const* d_in, const int* in_sizes, int n_in,
                              void* d_out, int out_size, void* d_ws, size_t ws_size,
                              hipStream_t stream) {
  const float* x     = (const float*)d_in[0];
  const float* enc_W = (const float*)d_in[1];
  const float* enc_b = (const float*)d_in[2];
  const float* bn1_g = (const float*)d_in[3];
  const float* bn1_b = (const float*)d_in[4];
  const float* Wqkv  = (const float*)d_in[5];
  const float* bqkv  = (const float*)d_in[6];
  const float* Wo    = (const float*)d_in[7];
  const float* bo    = (const float*)d_in[8];
  const float* W1    = (const float*)d_in[9];
  const float* b1    = (const float*)d_in[10];
  const float* bn2_g = (const float*)d_in[11];
  const float* bn2_b = (const float*)d_in[12];
  const float* W2    = (const float*)d_in[13];
  const float* b2    = (const float*)d_in[14];
  const float* Wc    = (const float*)d_in[15];
  const float* bc    = (const float*)d_in[16];

  char* ws = (char*)d_ws;
  size_t off = 0;
  auto alloc = [&](size_t bytes) -> void* {
    void* p = ws + off;
    off += (bytes + 255) & ~(size_t)255;
    return p;
  };

  unsigned short* yT     = (unsigned short*)alloc((size_t)CONCAT_ * B_ * 2); // bf16; reused for Z(f32)
  float*          pS1b   = (float*)alloc((size_t)NSLOT_ * PSTR_ * 4);
  float*          pS2b   = (float*)alloc((size_t)NSLOT_ * PSTR_ * 4);
  float*          mean1  = (float*)alloc(CONCAT_ * 4);
  float*          rstd1  = (float*)alloc(CONCAT_ * 4);
  unsigned short* Ybf    = (unsigned short*)alloc((size_t)B_ * E_ * 2);
  unsigned short* Rbf    = (unsigned short*)alloc((size_t)B_ * HID_ * 2);
  unsigned short* WoT_bf = (unsigned short*)alloc((size_t)E_ * E_ * 2);
  unsigned short* WvT_bf = (unsigned short*)alloc((size_t)E_ * E_ * 2);
  unsigned short* W1_bf  = (unsigned short*)alloc((size_t)HID_ * E_ * 2);
  unsigned short* W2_bf  = (unsigned short*)alloc((size_t)NREG_ * HID_ * 2);
  unsigned short* Wa_bf  = (unsigned short*)alloc((size_t)HID_ * E_ * 2);
  unsigned short* Wb_bf  = (unsigned short*)alloc((size_t)HID_ * E_ * 2);
  unsigned short* Wpk    = (unsigned short*)alloc((size_t)R_ * 2048 * 2);
  float*          Cpart  = (float*)alloc((size_t)4 * B_ * HID_ * 4);
  float*          t1v    = (float*)alloc(E_ * 4);
  float*          zbv    = (float*)alloc(HID_ * 4);
  float*          partS  = (float*)alloc((size_t)NS2_ * HID_ * 4);
  float*          partS2 = (float*)alloc((size_t)NS2_ * HID_ * 4);
  float*          mean2  = (float*)alloc(HID_ * 4);
  float*          rstd2  = (float*)alloc(HID_ * 4);
  int*            starts = (int*)alloc(R_ * 4);
  int*            redst  = (int*)alloc(R_ * 4);

  float* Z = (float*)yT;

  // 1. layout
  layout_kernel<<<1, 1, 0, stream>>>(starts, redst);
  // 2. P1: transposes || casts || rowdot1 || pack_w
  prep_kernel<<<2 * NTR_ + NCAST_ + E_ / 4 + R_, 256, 0, stream>>>(
      Wo, Wqkv + (size_t)2 * E_ * E_, WoT_bf, WvT_bf,
      W1, W1_bf, W2, W2_bf, bqkv + 2 * E_, bo, t1v, enc_W, starts, Wpk);
  // 3. MERGED: Wa gemm || encoder || rowdot2
  enc_wa_kernel<<<WA_NB_ + ENC_NB_ + HID_ / 4, 256, 0, stream>>>(
      x, Wpk, enc_b, starts, redst, yT, pS1b, pS2b, W1_bf, WoT_bf, Wa_bf, W1, t1v, b1, zbv);
  // 4. BN1 stats finalize
  bn1_stats_kernel<<<(CONCAT_ + 255) / 256, 256, 0, stream>>>(pS1b, pS2b, mean1, rstd1);
  // 5. MERGED: Wb gemm (KS2) || BN1 apply+transpose+pad
  trans_wb_kernel<<<WB_NB_ + TR_NB_, 256, 0, stream>>>(
      yT, mean1, rstd1, bn1_g, bn1_b, Ybf, Wa_bf, WvT_bf, Cpart);
  // 6. combine Wb -> bf16
  combine_wb_kernel<<<(HID_ * E_ + 255) / 256, 256, 0, stream>>>(Cpart, Wb_bf);
  // 7. Z = Y @ Wb^T (KS=4)
  gemm_kernel<4, false><<<dim3(HID_ / 128, B_ / 128, 4), 256, 0, stream>>>(
      Ybf, Wb_bf, Cpart, nullptr, B_, HID_, E_);
  // 8. Z combine + zb + BN2 partial stats
  combZ_stats_kernel<<<dim3(HID_ / 256, NS2_), 256, 0, stream>>>(Cpart, zbv, Z, partS, partS2);
  // 9. BN2 stats finalize
  colstats_final_kernel<<<(HID_ + 255) / 256, 256, 0, stream>>>(partS, partS2, mean2, rstd2);
  // 10. BN2 apply -> bf16
  bn2_apply_kernel<<<(B_ * HID_) / 256, 256, 0, stream>>>(Z, mean2, rstd2, bn2_g, bn2_b, Rbf);
  // 11. reg partials: R @ W2^T (KS=4)
  gemm_kernel<4, false><<<dim3((NREG_ + 127) / 128, B_ / 128, 4), 256, 0, stream>>>(
      Rbf, W2_bf, Cpart, nullptr, B_, NREG_, HID_);
  // 12. classifier (fused W2 combine) -> reg_out, y_pred
  float* reg_out = (float*)d_out;
  classifier_kernel<<<B_, 256, 0, stream>>>(
      Cpart, b2, Wc, bc, reg_out, reg_out + (size_t)B_ * NREG_);
}